// Round 10
// baseline (623.936 us; speedup 1.0000x reference)
//
#include <hip/hip_runtime.h>
#include <math.h>

#define T_SEQ 8192
#define D_MODEL 1024
#define DK 64
#define DKP 128
#define DV 64
#define C1LD 512   // padded fused-projection width (385 -> 512)
#define RMS_EPS 1.1920929e-07f
#define CHUNK 128
#define NCHUNK 64  // T_SEQ / CHUNK

typedef __attribute__((ext_vector_type(8))) __bf16 bf16x8;
typedef __attribute__((ext_vector_type(4))) float f32x4;

__device__ __forceinline__ float wave_sum(float x) {
#pragma unroll
  for (int off = 1; off < 64; off <<= 1) x += __shfl_xor(x, off, 64);
  return x;
}

// DPP row_ror rotate-reduce within 16-lane groups: VALU-pipe only, no LDS traffic.
template <int CTRL>
__device__ __forceinline__ float dpp_add(float x) {
  return x + __int_as_float(
                 __builtin_amdgcn_update_dpp(0, __float_as_int(x), CTRL, 0xF, 0xF, false));
}
__device__ __forceinline__ float sum16(float x) {
  x = dpp_add<0x121>(x);  // row_ror:1
  x = dpp_add<0x122>(x);  // row_ror:2
  x = dpp_add<0x124>(x);  // row_ror:4
  x = dpp_add<0x128>(x);  // row_ror:8
  return x;               // every lane holds the 16-lane sum
}

__device__ __forceinline__ float sigmoidf_(float x) { return 1.0f / (1.0f + expf(-x)); }
__device__ __forceinline__ float siluf_(float x) { return x / (1.0f + expf(-x)); }

__device__ __forceinline__ unsigned short f2bf(float f) {
  unsigned u = __float_as_uint(f);
  u += 0x7fff + ((u >> 16) & 1);  // RNE
  return (unsigned short)(u >> 16);
}

// ---------------- tables: f32 freq and f32 k-phase shift (match numpy f32 semantics) ------
__global__ void init_tables(const float* __restrict__ delta, float* __restrict__ freq,
                            float* __restrict__ shift) {
  int i = threadIdx.x;  // 64
  freq[i] = (float)pow(10000.0, (double)i / 64.0);
  float s = 1.0f / (1.0f + expf(-delta[i]));
  shift[i] = -6.2831855f * s;
}

// ---------------- concat weights (bf16, padded to 512 rows) ----------------
__global__ void build_wcat16(const float* __restrict__ Wq, const float* __restrict__ Wk,
                             const float* __restrict__ Wv, const float* __restrict__ Wa1,
                             const float* __restrict__ Wb, const float* __restrict__ Wg,
                             unsigned short* __restrict__ W16) {
  int idx = blockIdx.x * 256 + threadIdx.x;
  if (idx >= 512 * 1024) return;
  int row = idx >> 10, col = idx & 1023;
  float v = 0.f;
  if (row < 64) v = Wq[row * 1024 + col];
  else if (row < 128) v = Wk[(row - 64) * 1024 + col];
  else if (row < 192) v = Wv[(row - 128) * 1024 + col];
  else if (row < 320) v = Wa1[(row - 192) * 1024 + col];
  else if (row == 320) v = Wb[col];
  else if (row < 385) v = Wg[(row - 321) * 1024 + col];
  W16[idx] = f2bf(v);
}

// ---------------- f32 -> bf16 convert (float4 -> 4x bf16) ----------------
__global__ void conv_bf16(const float* __restrict__ in, unsigned short* __restrict__ out,
                          int n4) {
  int i = blockIdx.x * 256 + threadIdx.x;
  if (i >= n4) return;
  float4 v = ((const float4*)in)[i];
  uint2 o;
  o.x = (unsigned)f2bf(v.x) | ((unsigned)f2bf(v.y) << 16);
  o.y = (unsigned)f2bf(v.z) | ((unsigned)f2bf(v.w) << 16);
  ((uint2*)out)[i] = o;
}

// ---------------- fused weight conversions (Wg, Wu, Wd, W_out) ----------------
__global__ void conv_weights(const float* __restrict__ Wg, const float* __restrict__ Wu,
                             const float* __restrict__ Wd, const float* __restrict__ Wo,
                             unsigned short* __restrict__ Wg16, unsigned short* __restrict__ Wu16,
                             unsigned short* __restrict__ Wd16, unsigned short* __restrict__ Wo16) {
  int i = blockIdx.x * 256 + threadIdx.x;  // float4 groups
  const float* src;
  unsigned short* dst;
  int base;
  if (i < 262144) { src = Wg; dst = Wg16; base = i; }
  else if (i < 524288) { src = Wu; dst = Wu16; base = i - 262144; }
  else if (i < 786432) { src = Wd; dst = Wd16; base = i - 524288; }
  else if (i < 802816) { src = Wo; dst = Wo16; base = i - 786432; }
  else return;
  float4 v = ((const float4*)src)[base];
  uint2 o;
  o.x = (unsigned)f2bf(v.x) | ((unsigned)f2bf(v.y) << 16);
  o.y = (unsigned)f2bf(v.z) | ((unsigned)f2bf(v.w) << 16);
  ((uint2*)dst)[base] = o;
}

// ---------------- bf16 MFMA GEMM (m97 structure): C(f32) = act(A @ B^T [+ add]) ----------
__global__ __launch_bounds__(256) void gemm_bf16(const unsigned short* __restrict__ A,
                                                 const unsigned short* __restrict__ B,
                                                 const float* __restrict__ add,
                                                 float* __restrict__ C,
                                                 int M, int N, int K, int act) {
  __shared__ unsigned short As[128 * 32];
  __shared__ unsigned short Bs[128 * 32];
  const int tid = threadIdx.x;
  const int tm0 = blockIdx.x * 128, tn0 = blockIdx.y * 128;
  const int lane = tid & 63;
  const int w = tid >> 6;
  const int wr = (w >> 1) * 64, wc = (w & 1) * 64;
  const int fr = lane & 15, fq = lane >> 4;
  const int seg = w << 5;              // wave's 32-row segment of the tile
  const int srow = lane >> 2;          // 0..15 within a 16-row staging call
  const int skc = (lane & 3) * 8;      // k element offset (8 bf16 = 16 B)
  f32x4 acc[4][4];
#pragma unroll
  for (int a = 0; a < 4; ++a)
#pragma unroll
    for (int b = 0; b < 4; ++b) acc[a][b] = (f32x4){0.f, 0.f, 0.f, 0.f};

  for (int k0 = 0; k0 < K; k0 += 32) {
    __syncthreads();
#pragma unroll
    for (int j = 0; j < 2; ++j) {
      int r = seg + j * 16 + srow;
      __builtin_amdgcn_global_load_lds(
          (const __attribute__((address_space(1))) unsigned int*)(A + (size_t)(tm0 + r) * K + k0 + skc),
          (__attribute__((address_space(3))) unsigned int*)(As + (seg + j * 16) * 32),
          16, 0, 0);
      __builtin_amdgcn_global_load_lds(
          (const __attribute__((address_space(1))) unsigned int*)(B + (size_t)(tn0 + r) * K + k0 + skc),
          (__attribute__((address_space(3))) unsigned int*)(Bs + (seg + j * 16) * 32),
          16, 0, 0);
    }
    __syncthreads();
    bf16x8 af[4], bfr[4];
#pragma unroll
    for (int a = 0; a < 4; ++a)
      af[a] = *(const bf16x8*)(As + (wr + a * 16 + fr) * 32 + fq * 8);
#pragma unroll
    for (int b = 0; b < 4; ++b)
      bfr[b] = *(const bf16x8*)(Bs + (wc + b * 16 + fr) * 32 + fq * 8);
#pragma unroll
    for (int a = 0; a < 4; ++a)
#pragma unroll
      for (int b = 0; b < 4; ++b)
        acc[a][b] = __builtin_amdgcn_mfma_f32_16x16x32_bf16(af[a], bfr[b], acc[a][b], 0, 0, 0);
  }
#pragma unroll
  for (int a = 0; a < 4; ++a) {
#pragma unroll
    for (int b = 0; b < 4; ++b) {
#pragma unroll
      for (int r = 0; r < 4; ++r) {
        int row = tm0 + wr + a * 16 + fq * 4 + r;
        int col = tn0 + wc + b * 16 + fr;
        float v = acc[a][b][r];
        if (add) v += add[(size_t)row * N + col];
        if (act == 2) v = v / (1.0f + expf(-v));
        C[(size_t)row * N + col] = v;
      }
    }
  }
}

// ---------------- generic f32 GEMM (kept for the small alpha2 GEMM) ----------------
__global__ __launch_bounds__(256) void gemm_f32(const float* __restrict__ A,
                                                const float* __restrict__ B,
                                                const float* __restrict__ add,
                                                float* __restrict__ C,
                                                int M, int N, int K, int act) {
  __shared__ float As[16][68];
  __shared__ float Bs[16][68];
  const int bm = blockIdx.x * 64;
  const int bn = blockIdx.y * 64;
  const int tid = threadIdx.x;
  const int tm = tid >> 4, tn = tid & 15;
  const int lk = (tid & 3) << 2, lm = tid >> 2;
  float acc[4][4] = {{0.f}};
  const int ar = bm + lm;
  const int br = bn + lm;
  for (int k0 = 0; k0 < K; k0 += 16) {
    float4 a4 = make_float4(0.f, 0.f, 0.f, 0.f);
    float4 b4 = make_float4(0.f, 0.f, 0.f, 0.f);
    if (ar < M) a4 = *(const float4*)(A + (size_t)ar * K + k0 + lk);
    if (br < N) b4 = *(const float4*)(B + (size_t)br * K + k0 + lk);
    __syncthreads();
    As[lk][lm] = a4.x; As[lk + 1][lm] = a4.y; As[lk + 2][lm] = a4.z; As[lk + 3][lm] = a4.w;
    Bs[lk][lm] = b4.x; Bs[lk + 1][lm] = b4.y; Bs[lk + 2][lm] = b4.z; Bs[lk + 3][lm] = b4.w;
    __syncthreads();
#pragma unroll
    for (int kk = 0; kk < 16; ++kk) {
      float4 av = *(const float4*)&As[kk][tm << 2];
      float4 bv = *(const float4*)&Bs[kk][tn << 2];
      float a_[4] = {av.x, av.y, av.z, av.w};
      float b_[4] = {bv.x, bv.y, bv.z, bv.w};
#pragma unroll
      for (int i = 0; i < 4; ++i)
#pragma unroll
        for (int j = 0; j < 4; ++j) acc[i][j] = fmaf(a_[i], b_[j], acc[i][j]);
    }
  }
#pragma unroll
  for (int i = 0; i < 4; ++i) {
    int row = bm + (tm << 2) + i;
    if (row >= M) continue;
#pragma unroll
    for (int j = 0; j < 4; ++j) {
      int col = bn + (tn << 2) + j;
      if (col >= N) continue;
      float r = acc[i][j];
      if (add) r += add[(size_t)row * N + col];
      if (act == 1) r = 1.0f / (1.0f + expf(-r));
      else if (act == 2) r = r / (1.0f + expf(-r));
      C[(size_t)row * N + col] = r;
    }
  }
}

// ---------------- activations: v=silu, a1=silu, beta=sigmoid ----------------
__global__ void act_split(const float* __restrict__ C1, float* __restrict__ vb,
                          float* __restrict__ a1s, float* __restrict__ betab) {
  int idx = blockIdx.x * 256 + threadIdx.x;
  if (idx >= T_SEQ * 193) return;
  int t = idx / 193, j = idx % 193;
  if (j < 64) {
    float x = C1[(size_t)t * C1LD + 128 + j];
    vb[(size_t)t * DV + j] = siluf_(x);
  } else if (j < 192) {
    float x = C1[(size_t)t * C1LD + 192 + (j - 64)];
    a1s[(size_t)t * DKP + (j - 64)] = siluf_(x);
  } else {
    betab[t] = sigmoidf_(C1[(size_t)t * C1LD + 320]);
  }
}

// ---------------- PoPE: f32 phase arithmetic (matches numpy), accurate trig ----------------
__global__ __launch_bounds__(256) void pope_kernel(const float* __restrict__ C1,
                                                   const float* __restrict__ freq,
                                                   const float* __restrict__ shift,
                                                   float* __restrict__ qb, float* __restrict__ kb) {
  int idx = blockIdx.x * 256 + threadIdx.x;
  if (idx >= T_SEQ * DK) return;
  int t = idx >> 6;
  int i = idx & 63;
  const double TWO_PI = 6.283185307179586476925286766559;
  const double INV_TWO_PI = 0.15915494309189533576888376337251;
  float phiq = (float)t * freq[i];          // f32 multiply (matches numpy)
  float phik = phiq + shift[i];             // f32 add (matches numpy)
  float xq = C1[(size_t)t * C1LD + i];
  float muq = xq > 15.f ? xq : log1pf(expf(xq));
  double w = (double)phiq * INV_TWO_PI;
  w -= floor(w);
  float aq = (float)(w * TWO_PI);
  qb[(size_t)t * DKP + i] = muq * cosf(aq);
  qb[(size_t)t * DKP + 64 + i] = muq * sinf(aq);
  float xk = C1[(size_t)t * C1LD + DK + i];
  float muk = xk > 15.f ? xk : log1pf(expf(xk));
  double wk = (double)phik * INV_TWO_PI;
  wk -= floor(wk);
  float ak = (float)(wk * TWO_PI);
  kb[(size_t)t * DKP + i] = muk * cosf(ak);
  kb[(size_t)t * DKP + 64 + i] = muk * sinf(ak);
}

// ================= chunked scan (DPP rotate-reduce, no LDS-pipe traffic) =================
// Layout: 16 lanes per column, 8 k-dims per lane. fstate/sinbuf layout: [chunk][col][row]
// (coalesced for all producers/consumers).

// Pass A: tasks 0..127 basis columns (waves 0..31), 128..191 driven columns (waves 32..47).
__global__ __launch_bounds__(64) void scan_passA(const float* __restrict__ kb,
                                                 const float* __restrict__ alphab,
                                                 const float* __restrict__ vb,
                                                 const float* __restrict__ betab,
                                                 float* __restrict__ PT,
                                                 float* __restrict__ fstate) {
  const int chunk = blockIdx.x;
  const int w = blockIdx.y;            // 0..47
  const int l = threadIdx.x;
  const int sl = l & 15;
  const int task = w * 4 + (l >> 4);   // 0..191; isP is wave-uniform (128 % 4 == 0)
  const bool isP = (task < 128);
  const int c = isP ? 0 : (task - 128);
  const float* kc = kb + (size_t)chunk * CHUNK * DKP + sl * 8;
  const float* ac = alphab + (size_t)chunk * CHUNK * DKP + sl * 8;
  const float* vcol = vb + (size_t)chunk * CHUNK * DV + c;
  const float* bp = betab + (size_t)chunk * CHUNK;
  float s[8];
#pragma unroll
  for (int i = 0; i < 8; ++i) s[i] = (isP && (sl * 8 + i == task)) ? 1.f : 0.f;
  float4 k0 = *(const float4*)kc, k1 = *(const float4*)(kc + 4);
  float4 a0 = *(const float4*)ac, a1 = *(const float4*)(ac + 4);
  float vt = isP ? 0.f : vcol[0];
  float bt = bp[0];
  for (int t = 0; t < CHUNK; ++t) {
    const int tn = (t + 1 < CHUNK) ? t + 1 : CHUNK - 1;
    float4 nk0 = *(const float4*)(kc + (size_t)tn * DKP);
    float4 nk1 = *(const float4*)(kc + (size_t)tn * DKP + 4);
    float4 na0 = *(const float4*)(ac + (size_t)tn * DKP);
    float4 na1 = *(const float4*)(ac + (size_t)tn * DKP + 4);
    float nv = isP ? 0.f : vcol[(size_t)tn * DV];
    float nb = bp[tn];
    s[0] *= a0.x; s[1] *= a0.y; s[2] *= a0.z; s[3] *= a0.w;
    s[4] *= a1.x; s[5] *= a1.y; s[6] *= a1.z; s[7] *= a1.w;
    float e0 = fmaf(s[1], k0.y, s[0] * k0.x);
    float e1 = fmaf(s[3], k0.w, s[2] * k0.z);
    float e2 = fmaf(s[5], k1.y, s[4] * k1.x);
    float e3 = fmaf(s[7], k1.w, s[6] * k1.z);
    float d = sum16((e0 + e1) + (e2 + e3));
    float cf = bt * (vt - d);
    s[0] = fmaf(cf, k0.x, s[0]); s[1] = fmaf(cf, k0.y, s[1]);
    s[2] = fmaf(cf, k0.z, s[2]); s[3] = fmaf(cf, k0.w, s[3]);
    s[4] = fmaf(cf, k1.x, s[4]); s[5] = fmaf(cf, k1.y, s[5]);
    s[6] = fmaf(cf, k1.z, s[6]); s[7] = fmaf(cf, k1.w, s[7]);
    k0 = nk0; k1 = nk1; a0 = na0; a1 = na1; vt = nv; bt = nb;
  }
  if (isP) {
    float* dst = PT + (size_t)chunk * 16384 + (size_t)task * 128 + sl * 8;
    *(float4*)dst = make_float4(s[0], s[1], s[2], s[3]);
    *(float4*)(dst + 4) = make_float4(s[4], s[5], s[6], s[7]);
  } else {
    float* fd = fstate + (size_t)chunk * 8192 + (size_t)c * 128 + sl * 8;
    *(float4*)fd = make_float4(s[0], s[1], s[2], s[3]);
    *(float4*)(fd + 4) = make_float4(s[4], s[5], s[6], s[7]);
  }
}

// Combine v3: per column c, sequentially s_in(j+1) = P_j s_in(j) + f_j.
// 1024 threads = 128 rows x 8 K-eighths; 16-float register prefetch per thread (no spill);
// LDS tree-reduce of the 8 partials. fstate/sinbuf in [chunk][col][row] (coalesced).
__global__ __launch_bounds__(1024) void scan_combine(const float* __restrict__ PT,
                                                     const float* __restrict__ fstate,
                                                     float* __restrict__ sinbuf) {
  const int c = blockIdx.x;            // 0..63
  const int tid = threadIdx.x;
  const int r = tid & 127;             // row
  const int q = tid >> 7;              // K-eighth 0..7
  __shared__ float sv[128];
  __shared__ float part[8][128];
  const float* Pb = PT + (size_t)q * 2048 + r;  // + j*16384 + i*128
  float bufA[16], bufB[16];
#pragma unroll
  for (int i = 0; i < 16; ++i) bufA[i] = Pb[(size_t)i * 128];
  float s = 0.f;
#define CITER(J, CUR, NXT)                                                         \
  {                                                                                \
    float fJ = 0.f;                                                                \
    if (q == 0) {                                                                  \
      sinbuf[(size_t)(J) * 8192 + (size_t)c * 128 + r] = s;                        \
      sv[r] = s;                                                                   \
      fJ = fstate[(size_t)(J) * 8192 + (size_t)c * 128 + r];                       \
    }                                                                              \
    __syncthreads();                                                               \
    int jn = ((J) + 1 < NCHUNK) ? (J) + 1 : NCHUNK - 1;                            \
    const float* Pn = Pb + (size_t)jn * 16384;                                     \
    _Pragma("unroll")                                                              \
    for (int i = 0; i < 16; ++i) NXT[i] = Pn[(size_t)i * 128];                     \
    float a0 = 0.f, a1 = 0.f, a2 = 0.f, a3 = 0.f;                                  \
    _Pragma("unroll")                                                              \
    for (int i = 0; i < 16; i += 4) {                                              \
      a0 = fmaf(CUR[i], sv[q * 16 + i], a0);                                       \
      a1 = fmaf(CUR[i + 1], sv[q * 16 + i + 1], a1);                               \
      a2 = fmaf(CUR[i + 2], sv[q * 16 + i + 2], a2);                               \
      a3 = fmaf(CUR[i + 3], sv[q * 16 + i + 3], a3);                               \
    }                                                                              \
    part[q][r] = (a0 + a1) + (a2 + a3);                                            \
    __syncthreads();                                                               \
    if (q == 0) {                                                                  \
      float t8 = ((part[0][r] + part[1][r]) + (part[2][r] + part[3][r])) +         \
                 ((part[4][r] + part[5][r]) + (part[6][r] + part[7][r]));          \
      s = t8 + fJ;                                                                 \
    }                                                                              \
  }
  for (int j = 0; j < NCHUNK; j += 2) {
    CITER(j, bufA, bufB)
    CITER(j + 1, bufB, bufA)
  }
#undef CITER
}

// Pass B: 4 columns/wave, 2-deep software-pipelined loads, exact per-column scan.
struct PBIn {
  float4 k0, k1, a0, a1, q0, q1;
  float v, b;
};

__device__ __forceinline__ PBIn pb_load(const float* kc, const float* ac, const float* qc,
                                        const float* vcol, const float* bp, int t) {
  int tt = (t < CHUNK) ? t : CHUNK - 1;
  PBIn in;
  in.k0 = *(const float4*)(kc + (size_t)tt * DKP);
  in.k1 = *(const float4*)(kc + (size_t)tt * DKP + 4);
  in.a0 = *(const float4*)(ac + (size_t)tt * DKP);
  in.a1 = *(const float4*)(ac + (size_t)tt * DKP + 4);
  in.q0 = *(const float4*)(qc + (size_t)tt * DKP);
  in.q1 = *(const float4*)(qc + (size_t)tt * DKP + 4);
  in.v = vcol[(size_t)tt * DV];
  in.b = bp[tt];
  return in;
}

__device__ __forceinline__ void pb_step(float s[8], const PBIn& in, int sl, float* ocol, int t) {
  s[0] *= in.a0.x; s[1] *= in.a0.y; s[2] *= in.a0.z; s[3] *= in.a0.w;
  s[4] *= in.a1.x; s[5] *= in.a1.y; s[6] *= in.a1.z; s[7] *= in.a1.w;
  float e0 = fmaf(s[1], in.k0.y, s[0] * in.k0.x);
  float e1 = fmaf(s[3], in.k0.w, s[2] * in.k0.z);
  float e2 = fmaf(s[5], in.k1.y, s[4] * in.k1.x);
  float e3 = fmaf(s[7], in.k1.w, s[6] * in.k1.z);
  float d = sum16((e0 + e1) + (e2 + e3));
  float cf = in.b * (in.v - d);
  s[0] = fmaf(cf, in.k0.x, s[0]); s[1] = fmaf(cf, in.k0.y, s[1]);
  s[2] = fmaf(cf, in.k0.z, s[2]); s[3] = fmaf(cf, in.k0.w, s[3]);
  s[4] = fmaf(cf, in.k1.x, s[4]); s[5] = fmaf(cf, in.k1.y, s[5]);
  s[6] = fmaf(cf, in.k1.z, s[6]); s[7] = fmaf(cf, in.k1.w, s[7]);
  float f0 = fmaf(s[1], in.q0.y, s[0] * in.q0.x);
  float f1 = fmaf(s[3], in.q0.w, s[2] * in.q0.z);
  float f2 = fmaf(s[5], in.q1.y, s[4] * in.q1.x);
  float f3 = fmaf(s[7], in.q1.w, s[6] * in.q1.z);
  float e = sum16((f0 + f1) + (f2 + f3));
  if (sl == 0) ocol[(size_t)t * DV] = e;
}

__global__ __launch_bounds__(64) void scan_passB(const float* __restrict__ qb,
                                                 const float* __restrict__ kb,
                                                 const float* __restrict__ alphab,
                                                 const float* __restrict__ vb,
                                                 const float* __restrict__ betab,
                                                 const float* __restrict__ sinbuf,
                                                 float* __restrict__ ob) {
  const int chunk = blockIdx.x;
  const int l = threadIdx.x;
  const int sl = l & 15;
  const int c = blockIdx.y * 4 + (l >> 4);  // 0..63
  const float* kc = kb + (size_t)chunk * CHUNK * DKP + sl * 8;
  const float* ac = alphab + (size_t)chunk * CHUNK * DKP + sl * 8;
  const float* qc = qb + (size_t)chunk * CHUNK * DKP + sl * 8;
  const float* vcol = vb + (size_t)chunk * CHUNK * DV + c;
  const float* bp = betab + (size_t)chunk * CHUNK;
  float* ocol = ob + (size_t)chunk * CHUNK * DV + c;
  float s[8];
  const float* sbase = sinbuf + (size_t)chunk * 8192 + (size_t)c * 128 + sl * 8;
  float4 si0 = *(const float4*)sbase, si1 = *(const float4*)(sbase + 4);
  s[0] = si0.x; s[1] = si0.y; s[2] = si0.z; s[3] = si0.w;
  s[4] = si1.x; s[5] = si1.y; s[6] = si1.z; s[7] = si1.w;
  PBIn inA = pb_load(kc, ac, qc, vcol, bp, 0);
  PBIn inB = pb_load(kc, ac, qc, vcol, bp, 1);
  for (int t = 0; t < CHUNK; t += 2) {
    pb_step(s, inA, sl, ocol, t);
    inA = pb_load(kc, ac, qc, vcol, bp, t + 2);
    pb_step(s, inB, sl, ocol, t + 1);
    inB = pb_load(kc, ac, qc, vcol, bp, t + 3);
  }
}

// ---------------- post: og16 = bf16(rmsnorm(o)*pnw*sigmoid(gate_pre)) ----------------
__global__ __launch_bounds__(256) void post_kernel(const float* __restrict__ ob,
                                                   const float* __restrict__ C1,
                                                   const float* __restrict__ pnw,
                                                   unsigned short* __restrict__ og16) {
  int row = blockIdx.x * 4 + (threadIdx.x >> 6);
  int c = threadIdx.x & 63;
  float o = ob[(size_t)row * DV + c];
  float ss = wave_sum(o * o);
  float scale = 1.0f / sqrtf(ss * (1.0f / DV) + RMS_EPS);
  float g = sigmoidf_(C1[(size_t)row * C1LD + 321 + c]);
  og16[(size_t)row * DV + c] = f2bf(o * scale * pnw[c] * g);
}

// ---------------- rmsnorm over d=1024 rows -> bf16 ----------------
__global__ __launch_bounds__(256) void rmsnorm_rows(const float* __restrict__ x,
                                                    const float* __restrict__ w,
                                                    unsigned short* __restrict__ y) {
  int row = blockIdx.x;
  const float4* x4 = (const float4*)(x + (size_t)row * D_MODEL);
  const float4* w4 = (const float4*)w;
  float4 v = x4[threadIdx.x];
  float ss = v.x * v.x + v.y * v.y + v.z * v.z + v.w * v.w;
  ss = wave_sum(ss);
  __shared__ float red[4];
  if ((threadIdx.x & 63) == 0) red[threadIdx.x >> 6] = ss;
  __syncthreads();
  float tot = red[0] + red[1] + red[2] + red[3];
  float scale = 1.0f / sqrtf(tot * (1.0f / D_MODEL) + RMS_EPS);
  float4 wv = w4[threadIdx.x];
  uint2 o;
  o.x = (unsigned)f2bf(v.x * scale * wv.x) | ((unsigned)f2bf(v.y * scale * wv.y) << 16);
  o.y = (unsigned)f2bf(v.z * scale * wv.z) | ((unsigned)f2bf(v.w * scale * wv.w) << 16);
  ((uint2*)(y + (size_t)row * D_MODEL))[threadIdx.x] = o;
}

// ---------------- GU16 = bf16(G * U) ----------------
__global__ void mul_to_bf16(const float* __restrict__ G, const float* __restrict__ U,
                            unsigned short* __restrict__ O, int n4) {
  int i = blockIdx.x * 256 + threadIdx.x;
  if (i >= n4) return;
  float4 g = ((const float4*)G)[i];
  float4 u = ((const float4*)U)[i];
  uint2 o;
  o.x = (unsigned)f2bf(g.x * u.x) | ((unsigned)f2bf(g.y * u.y) << 16);
  o.y = (unsigned)f2bf(g.z * u.z) | ((unsigned)f2bf(g.w * u.w) << 16);
  ((uint2*)O)[i] = o;
}

extern "C" void kernel_launch(void* const* d_in, const int* in_sizes, int n_in,
                              void* d_out, int out_size, void* d_ws, size_t ws_size,
                              hipStream_t stream) {
  const float* x_seq = (const float*)d_in[0];
  const float* W_q = (const float*)d_in[1];
  const float* W_k = (const float*)d_in[2];
  const float* W_v = (const float*)d_in[3];
  const float* pope_delta = (const float*)d_in[4];
  const float* W_a1 = (const float*)d_in[5];
  const float* W_a2 = (const float*)d_in[6];
  const float* W_beta = (const float*)d_in[7];
  const float* pnw = (const float*)d_in[8];
  const float* out_gate_W = (const float*)d_in[9];
  const float* W_out = (const float*)d_in[10];
  const float* ffn_norm_w = (const float*)d_in[11];
  const float* Wg = (const float*)d_in[12];
  const float* Wu = (const float*)d_in[13];
  const float* Wd = (const float*)d_in[14];
  float* out = (float*)d_out;

  float* F = (float*)d_ws;
  float* freq_f = F;                      // 64
  float* shift_f = F + 64;                // 64
  size_t o = 256;
  unsigned short* Wcat16 = (unsigned short*)(F + o); o += 262144;   // 512x1024 bf16
  unsigned short* Wg16   = (unsigned short*)(F + o); o += 524288;   // 1024x1024 bf16
  unsigned short* Wu16   = (unsigned short*)(F + o); o += 524288;
  unsigned short* Wd16   = (unsigned short*)(F + o); o += 524288;
  unsigned short* Wout16 = (unsigned short*)(F + o); o += 32768;    // 1024x64 bf16
  unsigned short* og16   = (unsigned short*)(F + o); o += 262144;   // 8192x64 bf16
  float* BIG = F + o;
  // phase 1 layout (within BIG)
  float* C1 = BIG;                        // 8192x512 f32
  float* qb = C1 + 4194304;               // 8192x128
  float* kb = qb + 1048576;
  float* alphab = kb + 1048576;
  float* a1s = alphab + 1048576;
  float* vb = a1s + 1048576;              // 8192x64
  float* betab = vb + 524288;             // 8192
  float* ob = betab + 8192;               // 8192x64
  float* PT = ob + 524288;                // 64x128x128
  float* fstate = PT + 1048576;           // 64x64x128 [chunk][col][row]
  float* sinbuf = fstate + 524288;        // 64x64x128 [chunk][col][row]
  unsigned short* x16 = (unsigned short*)(sinbuf + 524288);  // 8192x1024 bf16
  // phase 2 layout (reuses BIG; phase-1 buffers dead by then)
  unsigned short* hb16 = (unsigned short*)BIG;   // 8192x1024 bf16
  unsigned short* GU16 = (unsigned short*)BIG;   // aliases hb16 (dead after Wu GEMM)
  float* Gb = BIG + 4194304;              // 8192x1024 f32
  float* Ub = Gb + 8388608;               // 8192x1024 f32

  (void)in_sizes; (void)n_in; (void)out_size; (void)ws_size;

  init_tables<<<1, 64, 0, stream>>>(pope_delta, freq_f, shift_f);
  build_wcat16<<<(512 * 1024 + 255) / 256, 256, 0, stream>>>(W_q, W_k, W_v, W_a1, W_beta,
                                                             out_gate_W, Wcat16);
  conv_bf16<<<(2097152 + 255) / 256, 256, 0, stream>>>(x_seq, x16, 2097152);
  conv_weights<<<(802816 + 255) / 256, 256, 0, stream>>>(Wg, Wu, Wd, W_out,
                                                         Wg16, Wu16, Wd16, Wout16);
  // fused projection: C1 = x16 @ Wcat16^T  (8192 x 512, K=1024)
  gemm_bf16<<<dim3(64, 4), 256, 0, stream>>>(x16, Wcat16, nullptr, C1, T_SEQ, 512, 1024, 0);
  act_split<<<(T_SEQ * 193 + 255) / 256, 256, 0, stream>>>(C1, vb, a1s, betab);
  gemm_f32<<<dim3(128, 2), 256, 0, stream>>>(a1s, W_a2, nullptr, alphab, T_SEQ, DKP, DKP, 1);
  pope_kernel<<<(T_SEQ * DK + 255) / 256, 256, 0, stream>>>(C1, freq_f, shift_f, qb, kb);
  // chunked scan
  scan_passA<<<dim3(NCHUNK, 48), 64, 0, stream>>>(kb, alphab, vb, betab, PT, fstate);
  scan_combine<<<64, 1024, 0, stream>>>(PT, fstate, sinbuf);
  scan_passB<<<dim3(NCHUNK, 16), 64, 0, stream>>>(qb, kb, alphab, vb, betab, sinbuf, ob);
  post_kernel<<<T_SEQ / 4, 256, 0, stream>>>(ob, C1, pnw, og16);
  // xres = x_seq + og @ W_out^T  (8192 x 1024, K=64) -> d_out
  gemm_bf16<<<dim3(64, 8), 256, 0, stream>>>(og16, Wout16, x_seq, out, T_SEQ, D_MODEL, 64, 0);
  rmsnorm_rows<<<T_SEQ, 256, 0, stream>>>(out, ffn_norm_w, hb16);
  // FFN
  gemm_bf16<<<dim3(64, 8), 256, 0, stream>>>(hb16, Wg16, nullptr, Gb, T_SEQ, D_MODEL, D_MODEL, 2);
  gemm_bf16<<<dim3(64, 8), 256, 0, stream>>>(hb16, Wu16, nullptr, Ub, T_SEQ, D_MODEL, D_MODEL, 0);
  mul_to_bf16<<<(2097152 + 255) / 256, 256, 0, stream>>>(Gb, Ub, GU16, 2097152);
  gemm_bf16<<<dim3(64, 8), 256, 0, stream>>>(GU16, Wd16, out, out, T_SEQ, D_MODEL, D_MODEL, 0);
}

// Round 11
// 495.918 us; speedup vs baseline: 1.2581x; 1.2581x over previous
//
#include <hip/hip_runtime.h>
#include <math.h>

#define T_SEQ 8192
#define D_MODEL 1024
#define DK 64
#define DKP 128
#define DV 64
#define C1LD 512   // padded fused-projection width (385 -> 512)
#define RMS_EPS 1.1920929e-07f
#define CHUNK 128
#define NCHUNK 64  // T_SEQ / CHUNK

typedef __attribute__((ext_vector_type(8))) __bf16 bf16x8;
typedef __attribute__((ext_vector_type(4))) float f32x4;

__device__ __forceinline__ float wave_sum(float x) {
#pragma unroll
  for (int off = 1; off < 64; off <<= 1) x += __shfl_xor(x, off, 64);
  return x;
}

// DPP row_ror rotate-reduce within 16-lane groups: VALU-pipe only, no LDS traffic.
template <int CTRL>
__device__ __forceinline__ float dpp_add(float x) {
  return x + __int_as_float(
                 __builtin_amdgcn_update_dpp(0, __float_as_int(x), CTRL, 0xF, 0xF, false));
}
__device__ __forceinline__ float sum16(float x) {
  x = dpp_add<0x121>(x);  // row_ror:1
  x = dpp_add<0x122>(x);  // row_ror:2
  x = dpp_add<0x124>(x);  // row_ror:4
  x = dpp_add<0x128>(x);  // row_ror:8
  return x;               // every lane holds the 16-lane sum
}

__device__ __forceinline__ float sigmoidf_(float x) { return 1.0f / (1.0f + expf(-x)); }
__device__ __forceinline__ float siluf_(float x) { return x / (1.0f + expf(-x)); }

__device__ __forceinline__ unsigned short f2bf(float f) {
  unsigned u = __float_as_uint(f);
  u += 0x7fff + ((u >> 16) & 1);  // RNE
  return (unsigned short)(u >> 16);
}

// ---------------- tables: f32 freq and f32 k-phase shift (match numpy f32 semantics) ------
__global__ void init_tables(const float* __restrict__ delta, float* __restrict__ freq,
                            float* __restrict__ shift) {
  int i = threadIdx.x;  // 64
  freq[i] = (float)pow(10000.0, (double)i / 64.0);
  float s = 1.0f / (1.0f + expf(-delta[i]));
  shift[i] = -6.2831855f * s;
}

// ---------------- concat weights (bf16, padded to 512 rows) ----------------
__global__ void build_wcat16(const float* __restrict__ Wq, const float* __restrict__ Wk,
                             const float* __restrict__ Wv, const float* __restrict__ Wa1,
                             const float* __restrict__ Wb, const float* __restrict__ Wg,
                             unsigned short* __restrict__ W16) {
  int idx = blockIdx.x * 256 + threadIdx.x;
  if (idx >= 512 * 1024) return;
  int row = idx >> 10, col = idx & 1023;
  float v = 0.f;
  if (row < 64) v = Wq[row * 1024 + col];
  else if (row < 128) v = Wk[(row - 64) * 1024 + col];
  else if (row < 192) v = Wv[(row - 128) * 1024 + col];
  else if (row < 320) v = Wa1[(row - 192) * 1024 + col];
  else if (row == 320) v = Wb[col];
  else if (row < 385) v = Wg[(row - 321) * 1024 + col];
  W16[idx] = f2bf(v);
}

// ---------------- f32 -> bf16 convert (float4 -> 4x bf16) ----------------
__global__ void conv_bf16(const float* __restrict__ in, unsigned short* __restrict__ out,
                          int n4) {
  int i = blockIdx.x * 256 + threadIdx.x;
  if (i >= n4) return;
  float4 v = ((const float4*)in)[i];
  uint2 o;
  o.x = (unsigned)f2bf(v.x) | ((unsigned)f2bf(v.y) << 16);
  o.y = (unsigned)f2bf(v.z) | ((unsigned)f2bf(v.w) << 16);
  ((uint2*)out)[i] = o;
}

// ---------------- fused weight conversions (Wg, Wu, Wd, W_out) ----------------
__global__ void conv_weights(const float* __restrict__ Wg, const float* __restrict__ Wu,
                             const float* __restrict__ Wd, const float* __restrict__ Wo,
                             unsigned short* __restrict__ Wg16, unsigned short* __restrict__ Wu16,
                             unsigned short* __restrict__ Wd16, unsigned short* __restrict__ Wo16) {
  int i = blockIdx.x * 256 + threadIdx.x;  // float4 groups
  const float* src;
  unsigned short* dst;
  int base;
  if (i < 262144) { src = Wg; dst = Wg16; base = i; }
  else if (i < 524288) { src = Wu; dst = Wu16; base = i - 262144; }
  else if (i < 786432) { src = Wd; dst = Wd16; base = i - 524288; }
  else if (i < 802816) { src = Wo; dst = Wo16; base = i - 786432; }
  else return;
  float4 v = ((const float4*)src)[base];
  uint2 o;
  o.x = (unsigned)f2bf(v.x) | ((unsigned)f2bf(v.y) << 16);
  o.y = (unsigned)f2bf(v.z) | ((unsigned)f2bf(v.w) << 16);
  ((uint2*)dst)[base] = o;
}

// ---------------- bf16 MFMA GEMM (m97 structure): C(f32) = act(A @ B^T [+ add]) ----------
__global__ __launch_bounds__(256) void gemm_bf16(const unsigned short* __restrict__ A,
                                                 const unsigned short* __restrict__ B,
                                                 const float* __restrict__ add,
                                                 float* __restrict__ C,
                                                 int M, int N, int K, int act) {
  __shared__ unsigned short As[128 * 32];
  __shared__ unsigned short Bs[128 * 32];
  const int tid = threadIdx.x;
  const int tm0 = blockIdx.x * 128, tn0 = blockIdx.y * 128;
  const int lane = tid & 63;
  const int w = tid >> 6;
  const int wr = (w >> 1) * 64, wc = (w & 1) * 64;
  const int fr = lane & 15, fq = lane >> 4;
  const int seg = w << 5;              // wave's 32-row segment of the tile
  const int srow = lane >> 2;          // 0..15 within a 16-row staging call
  const int skc = (lane & 3) * 8;      // k element offset (8 bf16 = 16 B)
  f32x4 acc[4][4];
#pragma unroll
  for (int a = 0; a < 4; ++a)
#pragma unroll
    for (int b = 0; b < 4; ++b) acc[a][b] = (f32x4){0.f, 0.f, 0.f, 0.f};

  for (int k0 = 0; k0 < K; k0 += 32) {
    __syncthreads();
#pragma unroll
    for (int j = 0; j < 2; ++j) {
      int r = seg + j * 16 + srow;
      __builtin_amdgcn_global_load_lds(
          (const __attribute__((address_space(1))) unsigned int*)(A + (size_t)(tm0 + r) * K + k0 + skc),
          (__attribute__((address_space(3))) unsigned int*)(As + (seg + j * 16) * 32),
          16, 0, 0);
      __builtin_amdgcn_global_load_lds(
          (const __attribute__((address_space(1))) unsigned int*)(B + (size_t)(tn0 + r) * K + k0 + skc),
          (__attribute__((address_space(3))) unsigned int*)(Bs + (seg + j * 16) * 32),
          16, 0, 0);
    }
    __syncthreads();
    bf16x8 af[4], bfr[4];
#pragma unroll
    for (int a = 0; a < 4; ++a)
      af[a] = *(const bf16x8*)(As + (wr + a * 16 + fr) * 32 + fq * 8);
#pragma unroll
    for (int b = 0; b < 4; ++b)
      bfr[b] = *(const bf16x8*)(Bs + (wc + b * 16 + fr) * 32 + fq * 8);
#pragma unroll
    for (int a = 0; a < 4; ++a)
#pragma unroll
      for (int b = 0; b < 4; ++b)
        acc[a][b] = __builtin_amdgcn_mfma_f32_16x16x32_bf16(af[a], bfr[b], acc[a][b], 0, 0, 0);
  }
#pragma unroll
  for (int a = 0; a < 4; ++a) {
#pragma unroll
    for (int b = 0; b < 4; ++b) {
#pragma unroll
      for (int r = 0; r < 4; ++r) {
        int row = tm0 + wr + a * 16 + fq * 4 + r;
        int col = tn0 + wc + b * 16 + fr;
        float v = acc[a][b][r];
        if (add) v += add[(size_t)row * N + col];
        if (act == 2) v = v / (1.0f + expf(-v));
        C[(size_t)row * N + col] = v;
      }
    }
  }
}

// ---------------- generic f32 GEMM (kept for the small alpha2 GEMM) ----------------
__global__ __launch_bounds__(256) void gemm_f32(const float* __restrict__ A,
                                                const float* __restrict__ B,
                                                const float* __restrict__ add,
                                                float* __restrict__ C,
                                                int M, int N, int K, int act) {
  __shared__ float As[16][68];
  __shared__ float Bs[16][68];
  const int bm = blockIdx.x * 64;
  const int bn = blockIdx.y * 64;
  const int tid = threadIdx.x;
  const int tm = tid >> 4, tn = tid & 15;
  const int lk = (tid & 3) << 2, lm = tid >> 2;
  float acc[4][4] = {{0.f}};
  const int ar = bm + lm;
  const int br = bn + lm;
  for (int k0 = 0; k0 < K; k0 += 16) {
    float4 a4 = make_float4(0.f, 0.f, 0.f, 0.f);
    float4 b4 = make_float4(0.f, 0.f, 0.f, 0.f);
    if (ar < M) a4 = *(const float4*)(A + (size_t)ar * K + k0 + lk);
    if (br < N) b4 = *(const float4*)(B + (size_t)br * K + k0 + lk);
    __syncthreads();
    As[lk][lm] = a4.x; As[lk + 1][lm] = a4.y; As[lk + 2][lm] = a4.z; As[lk + 3][lm] = a4.w;
    Bs[lk][lm] = b4.x; Bs[lk + 1][lm] = b4.y; Bs[lk + 2][lm] = b4.z; Bs[lk + 3][lm] = b4.w;
    __syncthreads();
#pragma unroll
    for (int kk = 0; kk < 16; ++kk) {
      float4 av = *(const float4*)&As[kk][tm << 2];
      float4 bv = *(const float4*)&Bs[kk][tn << 2];
      float a_[4] = {av.x, av.y, av.z, av.w};
      float b_[4] = {bv.x, bv.y, bv.z, bv.w};
#pragma unroll
      for (int i = 0; i < 4; ++i)
#pragma unroll
        for (int j = 0; j < 4; ++j) acc[i][j] = fmaf(a_[i], b_[j], acc[i][j]);
    }
  }
#pragma unroll
  for (int i = 0; i < 4; ++i) {
    int row = bm + (tm << 2) + i;
    if (row >= M) continue;
#pragma unroll
    for (int j = 0; j < 4; ++j) {
      int col = bn + (tn << 2) + j;
      if (col >= N) continue;
      float r = acc[i][j];
      if (add) r += add[(size_t)row * N + col];
      if (act == 1) r = 1.0f / (1.0f + expf(-r));
      else if (act == 2) r = r / (1.0f + expf(-r));
      C[(size_t)row * N + col] = r;
    }
  }
}

// ---------------- activations: v=silu, a1=silu, beta=sigmoid ----------------
__global__ void act_split(const float* __restrict__ C1, float* __restrict__ vb,
                          float* __restrict__ a1s, float* __restrict__ betab) {
  int idx = blockIdx.x * 256 + threadIdx.x;
  if (idx >= T_SEQ * 193) return;
  int t = idx / 193, j = idx % 193;
  if (j < 64) {
    float x = C1[(size_t)t * C1LD + 128 + j];
    vb[(size_t)t * DV + j] = siluf_(x);
  } else if (j < 192) {
    float x = C1[(size_t)t * C1LD + 192 + (j - 64)];
    a1s[(size_t)t * DKP + (j - 64)] = siluf_(x);
  } else {
    betab[t] = sigmoidf_(C1[(size_t)t * C1LD + 320]);
  }
}

// ---------------- PoPE: f32 phase arithmetic (matches numpy), accurate trig ----------------
__global__ __launch_bounds__(256) void pope_kernel(const float* __restrict__ C1,
                                                   const float* __restrict__ freq,
                                                   const float* __restrict__ shift,
                                                   float* __restrict__ qb, float* __restrict__ kb) {
  int idx = blockIdx.x * 256 + threadIdx.x;
  if (idx >= T_SEQ * DK) return;
  int t = idx >> 6;
  int i = idx & 63;
  const double TWO_PI = 6.283185307179586476925286766559;
  const double INV_TWO_PI = 0.15915494309189533576888376337251;
  float phiq = (float)t * freq[i];          // f32 multiply (matches numpy)
  float phik = phiq + shift[i];             // f32 add (matches numpy)
  float xq = C1[(size_t)t * C1LD + i];
  float muq = xq > 15.f ? xq : log1pf(expf(xq));
  double w = (double)phiq * INV_TWO_PI;
  w -= floor(w);
  float aq = (float)(w * TWO_PI);
  qb[(size_t)t * DKP + i] = muq * cosf(aq);
  qb[(size_t)t * DKP + 64 + i] = muq * sinf(aq);
  float xk = C1[(size_t)t * C1LD + DK + i];
  float muk = xk > 15.f ? xk : log1pf(expf(xk));
  double wk = (double)phik * INV_TWO_PI;
  wk -= floor(wk);
  float ak = (float)(wk * TWO_PI);
  kb[(size_t)t * DKP + i] = muk * cosf(ak);
  kb[(size_t)t * DKP + 64 + i] = muk * sinf(ak);
}

// ================= chunked scan (DPP rotate-reduce, no LDS-pipe traffic) =================
// Layout: 16 lanes per column, 8 k-dims per lane. fstate/sinbuf layout: [chunk][col][row]
// (coalesced for all producers/consumers).

// Pass A: tasks 0..127 basis columns (waves 0..31), 128..191 driven columns (waves 32..47).
__global__ __launch_bounds__(64) void scan_passA(const float* __restrict__ kb,
                                                 const float* __restrict__ alphab,
                                                 const float* __restrict__ vb,
                                                 const float* __restrict__ betab,
                                                 float* __restrict__ PT,
                                                 float* __restrict__ fstate) {
  const int chunk = blockIdx.x;
  const int w = blockIdx.y;            // 0..47
  const int l = threadIdx.x;
  const int sl = l & 15;
  const int task = w * 4 + (l >> 4);   // 0..191; isP is wave-uniform (128 % 4 == 0)
  const bool isP = (task < 128);
  const int c = isP ? 0 : (task - 128);
  const float* kc = kb + (size_t)chunk * CHUNK * DKP + sl * 8;
  const float* ac = alphab + (size_t)chunk * CHUNK * DKP + sl * 8;
  const float* vcol = vb + (size_t)chunk * CHUNK * DV + c;
  const float* bp = betab + (size_t)chunk * CHUNK;
  float s[8];
#pragma unroll
  for (int i = 0; i < 8; ++i) s[i] = (isP && (sl * 8 + i == task)) ? 1.f : 0.f;
  float4 k0 = *(const float4*)kc, k1 = *(const float4*)(kc + 4);
  float4 a0 = *(const float4*)ac, a1 = *(const float4*)(ac + 4);
  float vt = isP ? 0.f : vcol[0];
  float bt = bp[0];
  for (int t = 0; t < CHUNK; ++t) {
    const int tn = (t + 1 < CHUNK) ? t + 1 : CHUNK - 1;
    float4 nk0 = *(const float4*)(kc + (size_t)tn * DKP);
    float4 nk1 = *(const float4*)(kc + (size_t)tn * DKP + 4);
    float4 na0 = *(const float4*)(ac + (size_t)tn * DKP);
    float4 na1 = *(const float4*)(ac + (size_t)tn * DKP + 4);
    float nv = isP ? 0.f : vcol[(size_t)tn * DV];
    float nb = bp[tn];
    s[0] *= a0.x; s[1] *= a0.y; s[2] *= a0.z; s[3] *= a0.w;
    s[4] *= a1.x; s[5] *= a1.y; s[6] *= a1.z; s[7] *= a1.w;
    float e0 = fmaf(s[1], k0.y, s[0] * k0.x);
    float e1 = fmaf(s[3], k0.w, s[2] * k0.z);
    float e2 = fmaf(s[5], k1.y, s[4] * k1.x);
    float e3 = fmaf(s[7], k1.w, s[6] * k1.z);
    float d = sum16((e0 + e1) + (e2 + e3));
    float cf = bt * (vt - d);
    s[0] = fmaf(cf, k0.x, s[0]); s[1] = fmaf(cf, k0.y, s[1]);
    s[2] = fmaf(cf, k0.z, s[2]); s[3] = fmaf(cf, k0.w, s[3]);
    s[4] = fmaf(cf, k1.x, s[4]); s[5] = fmaf(cf, k1.y, s[5]);
    s[6] = fmaf(cf, k1.z, s[6]); s[7] = fmaf(cf, k1.w, s[7]);
    k0 = nk0; k1 = nk1; a0 = na0; a1 = na1; vt = nv; bt = nb;
  }
  if (isP) {
    float* dst = PT + (size_t)chunk * 16384 + (size_t)task * 128 + sl * 8;
    *(float4*)dst = make_float4(s[0], s[1], s[2], s[3]);
    *(float4*)(dst + 4) = make_float4(s[4], s[5], s[6], s[7]);
  } else {
    float* fd = fstate + (size_t)chunk * 8192 + (size_t)c * 128 + sl * 8;
    *(float4*)fd = make_float4(s[0], s[1], s[2], s[3]);
    *(float4*)(fd + 4) = make_float4(s[4], s[5], s[6], s[7]);
  }
}

// Combine v3: per column c, sequentially s_in(j+1) = P_j s_in(j) + f_j.
// 1024 threads = 128 rows x 8 K-eighths; 16-float register prefetch per thread (no spill);
// LDS tree-reduce of the 8 partials. fstate/sinbuf in [chunk][col][row] (coalesced).
__global__ __launch_bounds__(1024) void scan_combine(const float* __restrict__ PT,
                                                     const float* __restrict__ fstate,
                                                     float* __restrict__ sinbuf) {
  const int c = blockIdx.x;            // 0..63
  const int tid = threadIdx.x;
  const int r = tid & 127;             // row
  const int q = tid >> 7;              // K-eighth 0..7
  __shared__ float sv[128];
  __shared__ float part[8][128];
  const float* Pb = PT + (size_t)q * 2048 + r;  // + j*16384 + i*128
  float bufA[16], bufB[16];
#pragma unroll
  for (int i = 0; i < 16; ++i) bufA[i] = Pb[(size_t)i * 128];
  float s = 0.f;
#define CITER(J, CUR, NXT)                                                         \
  {                                                                                \
    float fJ = 0.f;                                                                \
    if (q == 0) {                                                                  \
      sinbuf[(size_t)(J) * 8192 + (size_t)c * 128 + r] = s;                        \
      sv[r] = s;                                                                   \
      fJ = fstate[(size_t)(J) * 8192 + (size_t)c * 128 + r];                       \
    }                                                                              \
    __syncthreads();                                                               \
    int jn = ((J) + 1 < NCHUNK) ? (J) + 1 : NCHUNK - 1;                            \
    const float* Pn = Pb + (size_t)jn * 16384;                                     \
    _Pragma("unroll")                                                              \
    for (int i = 0; i < 16; ++i) NXT[i] = Pn[(size_t)i * 128];                     \
    float a0 = 0.f, a1 = 0.f, a2 = 0.f, a3 = 0.f;                                  \
    _Pragma("unroll")                                                              \
    for (int i = 0; i < 16; i += 4) {                                              \
      a0 = fmaf(CUR[i], sv[q * 16 + i], a0);                                       \
      a1 = fmaf(CUR[i + 1], sv[q * 16 + i + 1], a1);                               \
      a2 = fmaf(CUR[i + 2], sv[q * 16 + i + 2], a2);                               \
      a3 = fmaf(CUR[i + 3], sv[q * 16 + i + 3], a3);                               \
    }                                                                              \
    part[q][r] = (a0 + a1) + (a2 + a3);                                            \
    __syncthreads();                                                               \
    if (q == 0) {                                                                  \
      float t8 = ((part[0][r] + part[1][r]) + (part[2][r] + part[3][r])) +         \
                 ((part[4][r] + part[5][r]) + (part[6][r] + part[7][r]));          \
      s = t8 + fJ;                                                                 \
    }                                                                              \
  }
  for (int j = 0; j < NCHUNK; j += 2) {
    CITER(j, bufA, bufB)
    CITER(j + 1, bufB, bufA)
  }
#undef CITER
}

// Pass B: 4 columns/wave, r7-proven structure: next-iteration values loaded as named
// float4s at loop top (1-deep prefetch the compiler keeps in registers), compute after.
__global__ __launch_bounds__(64) void scan_passB(const float* __restrict__ qb,
                                                 const float* __restrict__ kb,
                                                 const float* __restrict__ alphab,
                                                 const float* __restrict__ vb,
                                                 const float* __restrict__ betab,
                                                 const float* __restrict__ sinbuf,
                                                 float* __restrict__ ob) {
  const int chunk = blockIdx.x;
  const int l = threadIdx.x;
  const int sl = l & 15;
  const int c = blockIdx.y * 4 + (l >> 4);  // 0..63
  const float* kc = kb + (size_t)chunk * CHUNK * DKP + sl * 8;
  const float* ac = alphab + (size_t)chunk * CHUNK * DKP + sl * 8;
  const float* qc = qb + (size_t)chunk * CHUNK * DKP + sl * 8;
  const float* vcol = vb + (size_t)chunk * CHUNK * DV + c;
  const float* bp = betab + (size_t)chunk * CHUNK;
  float* ocol = ob + (size_t)chunk * CHUNK * DV + c;
  float s[8];
  const float* sbase = sinbuf + (size_t)chunk * 8192 + (size_t)c * 128 + sl * 8;
  float4 si0 = *(const float4*)sbase, si1 = *(const float4*)(sbase + 4);
  s[0] = si0.x; s[1] = si0.y; s[2] = si0.z; s[3] = si0.w;
  s[4] = si1.x; s[5] = si1.y; s[6] = si1.z; s[7] = si1.w;
  float4 k0 = *(const float4*)kc, k1 = *(const float4*)(kc + 4);
  float4 a0 = *(const float4*)ac, a1 = *(const float4*)(ac + 4);
  float4 q0 = *(const float4*)qc, q1 = *(const float4*)(qc + 4);
  float vt = vcol[0], bt = bp[0];
  for (int t = 0; t < CHUNK; ++t) {
    const int tn = (t + 1 < CHUNK) ? t + 1 : CHUNK - 1;
    float4 nk0 = *(const float4*)(kc + (size_t)tn * DKP);
    float4 nk1 = *(const float4*)(kc + (size_t)tn * DKP + 4);
    float4 na0 = *(const float4*)(ac + (size_t)tn * DKP);
    float4 na1 = *(const float4*)(ac + (size_t)tn * DKP + 4);
    float4 nq0 = *(const float4*)(qc + (size_t)tn * DKP);
    float4 nq1 = *(const float4*)(qc + (size_t)tn * DKP + 4);
    float nv = vcol[(size_t)tn * DV];
    float nb = bp[tn];
    s[0] *= a0.x; s[1] *= a0.y; s[2] *= a0.z; s[3] *= a0.w;
    s[4] *= a1.x; s[5] *= a1.y; s[6] *= a1.z; s[7] *= a1.w;
    float e0 = fmaf(s[1], k0.y, s[0] * k0.x);
    float e1 = fmaf(s[3], k0.w, s[2] * k0.z);
    float e2 = fmaf(s[5], k1.y, s[4] * k1.x);
    float e3 = fmaf(s[7], k1.w, s[6] * k1.z);
    float d = sum16((e0 + e1) + (e2 + e3));
    float cf = bt * (vt - d);
    s[0] = fmaf(cf, k0.x, s[0]); s[1] = fmaf(cf, k0.y, s[1]);
    s[2] = fmaf(cf, k0.z, s[2]); s[3] = fmaf(cf, k0.w, s[3]);
    s[4] = fmaf(cf, k1.x, s[4]); s[5] = fmaf(cf, k1.y, s[5]);
    s[6] = fmaf(cf, k1.z, s[6]); s[7] = fmaf(cf, k1.w, s[7]);
    float f0 = fmaf(s[1], q0.y, s[0] * q0.x);
    float f1 = fmaf(s[3], q0.w, s[2] * q0.z);
    float f2 = fmaf(s[5], q1.y, s[4] * q1.x);
    float f3 = fmaf(s[7], q1.w, s[6] * q1.z);
    float e = sum16((f0 + f1) + (f2 + f3));
    if (sl == 0) ocol[(size_t)t * DV] = e;
    k0 = nk0; k1 = nk1; a0 = na0; a1 = na1; q0 = nq0; q1 = nq1; vt = nv; bt = nb;
  }
}

// ---------------- post: og16 = bf16(rmsnorm(o)*pnw*sigmoid(gate_pre)) ----------------
__global__ __launch_bounds__(256) void post_kernel(const float* __restrict__ ob,
                                                   const float* __restrict__ C1,
                                                   const float* __restrict__ pnw,
                                                   unsigned short* __restrict__ og16) {
  int row = blockIdx.x * 4 + (threadIdx.x >> 6);
  int c = threadIdx.x & 63;
  float o = ob[(size_t)row * DV + c];
  float ss = wave_sum(o * o);
  float scale = 1.0f / sqrtf(ss * (1.0f / DV) + RMS_EPS);
  float g = sigmoidf_(C1[(size_t)row * C1LD + 321 + c]);
  og16[(size_t)row * DV + c] = f2bf(o * scale * pnw[c] * g);
}

// ---------------- rmsnorm over d=1024 rows -> bf16 ----------------
__global__ __launch_bounds__(256) void rmsnorm_rows(const float* __restrict__ x,
                                                    const float* __restrict__ w,
                                                    unsigned short* __restrict__ y) {
  int row = blockIdx.x;
  const float4* x4 = (const float4*)(x + (size_t)row * D_MODEL);
  const float4* w4 = (const float4*)w;
  float4 v = x4[threadIdx.x];
  float ss = v.x * v.x + v.y * v.y + v.z * v.z + v.w * v.w;
  ss = wave_sum(ss);
  __shared__ float red[4];
  if ((threadIdx.x & 63) == 0) red[threadIdx.x >> 6] = ss;
  __syncthreads();
  float tot = red[0] + red[1] + red[2] + red[3];
  float scale = 1.0f / sqrtf(tot * (1.0f / D_MODEL) + RMS_EPS);
  float4 wv = w4[threadIdx.x];
  uint2 o;
  o.x = (unsigned)f2bf(v.x * scale * wv.x) | ((unsigned)f2bf(v.y * scale * wv.y) << 16);
  o.y = (unsigned)f2bf(v.z * scale * wv.z) | ((unsigned)f2bf(v.w * scale * wv.w) << 16);
  ((uint2*)(y + (size_t)row * D_MODEL))[threadIdx.x] = o;
}

// ---------------- GU16 = bf16(G * U) ----------------
__global__ void mul_to_bf16(const float* __restrict__ G, const float* __restrict__ U,
                            unsigned short* __restrict__ O, int n4) {
  int i = blockIdx.x * 256 + threadIdx.x;
  if (i >= n4) return;
  float4 g = ((const float4*)G)[i];
  float4 u = ((const float4*)U)[i];
  uint2 o;
  o.x = (unsigned)f2bf(g.x * u.x) | ((unsigned)f2bf(g.y * u.y) << 16);
  o.y = (unsigned)f2bf(g.z * u.z) | ((unsigned)f2bf(g.w * u.w) << 16);
  ((uint2*)O)[i] = o;
}

extern "C" void kernel_launch(void* const* d_in, const int* in_sizes, int n_in,
                              void* d_out, int out_size, void* d_ws, size_t ws_size,
                              hipStream_t stream) {
  const float* x_seq = (const float*)d_in[0];
  const float* W_q = (const float*)d_in[1];
  const float* W_k = (const float*)d_in[2];
  const float* W_v = (const float*)d_in[3];
  const float* pope_delta = (const float*)d_in[4];
  const float* W_a1 = (const float*)d_in[5];
  const float* W_a2 = (const float*)d_in[6];
  const float* W_beta = (const float*)d_in[7];
  const float* pnw = (const float*)d_in[8];
  const float* out_gate_W = (const float*)d_in[9];
  const float* W_out = (const float*)d_in[10];
  const float* ffn_norm_w = (const float*)d_in[11];
  const float* Wg = (const float*)d_in[12];
  const float* Wu = (const float*)d_in[13];
  const float* Wd = (const float*)d_in[14];
  float* out = (float*)d_out;

  float* F = (float*)d_ws;
  float* freq_f = F;                      // 64
  float* shift_f = F + 64;                // 64
  size_t o = 256;
  unsigned short* Wcat16 = (unsigned short*)(F + o); o += 262144;   // 512x1024 bf16
  unsigned short* Wg16   = (unsigned short*)(F + o); o += 524288;   // 1024x1024 bf16
  unsigned short* Wu16   = (unsigned short*)(F + o); o += 524288;
  unsigned short* Wd16   = (unsigned short*)(F + o); o += 524288;
  unsigned short* Wout16 = (unsigned short*)(F + o); o += 32768;    // 1024x64 bf16
  unsigned short* og16   = (unsigned short*)(F + o); o += 262144;   // 8192x64 bf16
  float* BIG = F + o;
  // phase 1 layout (within BIG)
  float* C1 = BIG;                        // 8192x512 f32
  float* qb = C1 + 4194304;               // 8192x128
  float* kb = qb + 1048576;
  float* alphab = kb + 1048576;
  float* a1s = alphab + 1048576;
  float* vb = a1s + 1048576;              // 8192x64
  float* betab = vb + 524288;             // 8192
  float* ob = betab + 8192;               // 8192x64
  float* PT = ob + 524288;                // 64x128x128
  float* fstate = PT + 1048576;           // 64x64x128 [chunk][col][row]
  float* sinbuf = fstate + 524288;        // 64x64x128 [chunk][col][row]
  unsigned short* x16 = (unsigned short*)(sinbuf + 524288);  // 8192x1024 bf16
  // phase 2 layout (reuses BIG; phase-1 buffers dead by then)
  unsigned short* hb16 = (unsigned short*)BIG;   // 8192x1024 bf16
  unsigned short* GU16 = (unsigned short*)BIG;   // aliases hb16 (dead after Wu GEMM)
  float* Gb = BIG + 4194304;              // 8192x1024 f32
  float* Ub = Gb + 8388608;               // 8192x1024 f32

  (void)in_sizes; (void)n_in; (void)out_size; (void)ws_size;

  init_tables<<<1, 64, 0, stream>>>(pope_delta, freq_f, shift_f);
  build_wcat16<<<(512 * 1024 + 255) / 256, 256, 0, stream>>>(W_q, W_k, W_v, W_a1, W_beta,
                                                             out_gate_W, Wcat16);
  conv_bf16<<<(2097152 + 255) / 256, 256, 0, stream>>>(x_seq, x16, 2097152);
  conv_weights<<<(802816 + 255) / 256, 256, 0, stream>>>(Wg, Wu, Wd, W_out,
                                                         Wg16, Wu16, Wd16, Wout16);
  // fused projection: C1 = x16 @ Wcat16^T  (8192 x 512, K=1024)
  gemm_bf16<<<dim3(64, 4), 256, 0, stream>>>(x16, Wcat16, nullptr, C1, T_SEQ, 512, 1024, 0);
  act_split<<<(T_SEQ * 193 + 255) / 256, 256, 0, stream>>>(C1, vb, a1s, betab);
  gemm_f32<<<dim3(128, 2), 256, 0, stream>>>(a1s, W_a2, nullptr, alphab, T_SEQ, DKP, DKP, 1);
  pope_kernel<<<(T_SEQ * DK + 255) / 256, 256, 0, stream>>>(C1, freq_f, shift_f, qb, kb);
  // chunked scan
  scan_passA<<<dim3(NCHUNK, 48), 64, 0, stream>>>(kb, alphab, vb, betab, PT, fstate);
  scan_combine<<<64, 1024, 0, stream>>>(PT, fstate, sinbuf);
  scan_passB<<<dim3(NCHUNK, 16), 64, 0, stream>>>(qb, kb, alphab, vb, betab, sinbuf, ob);
  post_kernel<<<T_SEQ / 4, 256, 0, stream>>>(ob, C1, pnw, og16);
  // xres = x_seq + og @ W_out^T  (8192 x 1024, K=64) -> d_out
  gemm_bf16<<<dim3(64, 8), 256, 0, stream>>>(og16, Wout16, x_seq, out, T_SEQ, D_MODEL, 64, 0);
  rmsnorm_rows<<<T_SEQ, 256, 0, stream>>>(out, ffn_norm_w, hb16);
  // FFN
  gemm_bf16<<<dim3(64, 8), 256, 0, stream>>>(hb16, Wg16, nullptr, Gb, T_SEQ, D_MODEL, D_MODEL, 2);
  gemm_bf16<<<dim3(64, 8), 256, 0, stream>>>(hb16, Wu16, nullptr, Ub, T_SEQ, D_MODEL, D_MODEL, 0);
  mul_to_bf16<<<(2097152 + 255) / 256, 256, 0, stream>>>(Gb, Ub, GU16, 2097152);
  gemm_bf16<<<dim3(64, 8), 256, 0, stream>>>(GU16, Wd16, out, out, T_SEQ, D_MODEL, D_MODEL, 0);
}

// Round 13
// 491.714 us; speedup vs baseline: 1.2689x; 1.0085x over previous
//
#include <hip/hip_runtime.h>
#include <math.h>

#define T_SEQ 8192
#define D_MODEL 1024
#define DK 64
#define DKP 128
#define DV 64
#define C1LD 512   // padded fused-projection width (385 -> 512)
#define RMS_EPS 1.1920929e-07f
#define CHUNK 128
#define NCHUNK 64  // T_SEQ / CHUNK

typedef __attribute__((ext_vector_type(8))) __bf16 bf16x8;
typedef __attribute__((ext_vector_type(4))) float f32x4;

__device__ __forceinline__ float wave_sum(float x) {
#pragma unroll
  for (int off = 1; off < 64; off <<= 1) x += __shfl_xor(x, off, 64);
  return x;
}

// DPP row_ror rotate-reduce within 16-lane groups: VALU-pipe only, no LDS traffic.
template <int CTRL>
__device__ __forceinline__ float dpp_add(float x) {
  return x + __int_as_float(
                 __builtin_amdgcn_update_dpp(0, __float_as_int(x), CTRL, 0xF, 0xF, false));
}
__device__ __forceinline__ float sum16(float x) {
  x = dpp_add<0x121>(x);  // row_ror:1
  x = dpp_add<0x122>(x);  // row_ror:2
  x = dpp_add<0x124>(x);  // row_ror:4
  x = dpp_add<0x128>(x);  // row_ror:8
  return x;               // every lane holds the 16-lane sum
}

__device__ __forceinline__ float sigmoidf_(float x) { return 1.0f / (1.0f + expf(-x)); }
__device__ __forceinline__ float siluf_(float x) { return x / (1.0f + expf(-x)); }

__device__ __forceinline__ unsigned short f2bf(float f) {
  unsigned u = __float_as_uint(f);
  u += 0x7fff + ((u >> 16) & 1);  // RNE
  return (unsigned short)(u >> 16);
}

// ---------------- tables: f32 freq and f32 k-phase shift (match numpy f32 semantics) ------
__global__ void init_tables(const float* __restrict__ delta, float* __restrict__ freq,
                            float* __restrict__ shift) {
  int i = threadIdx.x;  // 64
  freq[i] = (float)pow(10000.0, (double)i / 64.0);
  float s = 1.0f / (1.0f + expf(-delta[i]));
  shift[i] = -6.2831855f * s;
}

// ---------------- concat weights (bf16, padded to 512 rows) ----------------
__global__ void build_wcat16(const float* __restrict__ Wq, const float* __restrict__ Wk,
                             const float* __restrict__ Wv, const float* __restrict__ Wa1,
                             const float* __restrict__ Wb, const float* __restrict__ Wg,
                             unsigned short* __restrict__ W16) {
  int idx = blockIdx.x * 256 + threadIdx.x;
  if (idx >= 512 * 1024) return;
  int row = idx >> 10, col = idx & 1023;
  float v = 0.f;
  if (row < 64) v = Wq[row * 1024 + col];
  else if (row < 128) v = Wk[(row - 64) * 1024 + col];
  else if (row < 192) v = Wv[(row - 128) * 1024 + col];
  else if (row < 320) v = Wa1[(row - 192) * 1024 + col];
  else if (row == 320) v = Wb[col];
  else if (row < 385) v = Wg[(row - 321) * 1024 + col];
  W16[idx] = f2bf(v);
}

// ---------------- f32 -> bf16 convert (float4 -> 4x bf16) ----------------
__global__ void conv_bf16(const float* __restrict__ in, unsigned short* __restrict__ out,
                          int n4) {
  int i = blockIdx.x * 256 + threadIdx.x;
  if (i >= n4) return;
  float4 v = ((const float4*)in)[i];
  uint2 o;
  o.x = (unsigned)f2bf(v.x) | ((unsigned)f2bf(v.y) << 16);
  o.y = (unsigned)f2bf(v.z) | ((unsigned)f2bf(v.w) << 16);
  ((uint2*)out)[i] = o;
}

// ---------------- fused weight conversions (Wg, Wu, Wd, W_out) ----------------
__global__ void conv_weights(const float* __restrict__ Wg, const float* __restrict__ Wu,
                             const float* __restrict__ Wd, const float* __restrict__ Wo,
                             unsigned short* __restrict__ Wg16, unsigned short* __restrict__ Wu16,
                             unsigned short* __restrict__ Wd16, unsigned short* __restrict__ Wo16) {
  int i = blockIdx.x * 256 + threadIdx.x;  // float4 groups
  const float* src;
  unsigned short* dst;
  int base;
  if (i < 262144) { src = Wg; dst = Wg16; base = i; }
  else if (i < 524288) { src = Wu; dst = Wu16; base = i - 262144; }
  else if (i < 786432) { src = Wd; dst = Wd16; base = i - 524288; }
  else if (i < 802816) { src = Wo; dst = Wo16; base = i - 786432; }
  else return;
  float4 v = ((const float4*)src)[base];
  uint2 o;
  o.x = (unsigned)f2bf(v.x) | ((unsigned)f2bf(v.y) << 16);
  o.y = (unsigned)f2bf(v.z) | ((unsigned)f2bf(v.w) << 16);
  ((uint2*)dst)[base] = o;
}

// ---------------- bf16 MFMA GEMM (m97 structure): C(f32) = act(A @ B^T [+ add]) ----------
__global__ __launch_bounds__(256) void gemm_bf16(const unsigned short* __restrict__ A,
                                                 const unsigned short* __restrict__ B,
                                                 const float* __restrict__ add,
                                                 float* __restrict__ C,
                                                 int M, int N, int K, int act) {
  __shared__ unsigned short As[128 * 32];
  __shared__ unsigned short Bs[128 * 32];
  const int tid = threadIdx.x;
  const int tm0 = blockIdx.x * 128, tn0 = blockIdx.y * 128;
  const int lane = tid & 63;
  const int w = tid >> 6;
  const int wr = (w >> 1) * 64, wc = (w & 1) * 64;
  const int fr = lane & 15, fq = lane >> 4;
  const int seg = w << 5;              // wave's 32-row segment of the tile
  const int srow = lane >> 2;          // 0..15 within a 16-row staging call
  const int skc = (lane & 3) * 8;      // k element offset (8 bf16 = 16 B)
  f32x4 acc[4][4];
#pragma unroll
  for (int a = 0; a < 4; ++a)
#pragma unroll
    for (int b = 0; b < 4; ++b) acc[a][b] = (f32x4){0.f, 0.f, 0.f, 0.f};

  for (int k0 = 0; k0 < K; k0 += 32) {
    __syncthreads();
#pragma unroll
    for (int j = 0; j < 2; ++j) {
      int r = seg + j * 16 + srow;
      __builtin_amdgcn_global_load_lds(
          (const __attribute__((address_space(1))) unsigned int*)(A + (size_t)(tm0 + r) * K + k0 + skc),
          (__attribute__((address_space(3))) unsigned int*)(As + (seg + j * 16) * 32),
          16, 0, 0);
      __builtin_amdgcn_global_load_lds(
          (const __attribute__((address_space(1))) unsigned int*)(B + (size_t)(tn0 + r) * K + k0 + skc),
          (__attribute__((address_space(3))) unsigned int*)(Bs + (seg + j * 16) * 32),
          16, 0, 0);
    }
    __syncthreads();
    bf16x8 af[4], bfr[4];
#pragma unroll
    for (int a = 0; a < 4; ++a)
      af[a] = *(const bf16x8*)(As + (wr + a * 16 + fr) * 32 + fq * 8);
#pragma unroll
    for (int b = 0; b < 4; ++b)
      bfr[b] = *(const bf16x8*)(Bs + (wc + b * 16 + fr) * 32 + fq * 8);
#pragma unroll
    for (int a = 0; a < 4; ++a)
#pragma unroll
      for (int b = 0; b < 4; ++b)
        acc[a][b] = __builtin_amdgcn_mfma_f32_16x16x32_bf16(af[a], bfr[b], acc[a][b], 0, 0, 0);
  }
#pragma unroll
  for (int a = 0; a < 4; ++a) {
#pragma unroll
    for (int b = 0; b < 4; ++b) {
#pragma unroll
      for (int r = 0; r < 4; ++r) {
        int row = tm0 + wr + a * 16 + fq * 4 + r;
        int col = tn0 + wc + b * 16 + fr;
        float v = acc[a][b][r];
        if (add) v += add[(size_t)row * N + col];
        if (act == 2) v = v / (1.0f + expf(-v));
        C[(size_t)row * N + col] = v;
      }
    }
  }
}

// ---------------- generic f32 GEMM (kept for the small alpha2 GEMM) ----------------
__global__ __launch_bounds__(256) void gemm_f32(const float* __restrict__ A,
                                                const float* __restrict__ B,
                                                const float* __restrict__ add,
                                                float* __restrict__ C,
                                                int M, int N, int K, int act) {
  __shared__ float As[16][68];
  __shared__ float Bs[16][68];
  const int bm = blockIdx.x * 64;
  const int bn = blockIdx.y * 64;
  const int tid = threadIdx.x;
  const int tm = tid >> 4, tn = tid & 15;
  const int lk = (tid & 3) << 2, lm = tid >> 2;
  float acc[4][4] = {{0.f}};
  const int ar = bm + lm;
  const int br = bn + lm;
  for (int k0 = 0; k0 < K; k0 += 16) {
    float4 a4 = make_float4(0.f, 0.f, 0.f, 0.f);
    float4 b4 = make_float4(0.f, 0.f, 0.f, 0.f);
    if (ar < M) a4 = *(const float4*)(A + (size_t)ar * K + k0 + lk);
    if (br < N) b4 = *(const float4*)(B + (size_t)br * K + k0 + lk);
    __syncthreads();
    As[lk][lm] = a4.x; As[lk + 1][lm] = a4.y; As[lk + 2][lm] = a4.z; As[lk + 3][lm] = a4.w;
    Bs[lk][lm] = b4.x; Bs[lk + 1][lm] = b4.y; Bs[lk + 2][lm] = b4.z; Bs[lk + 3][lm] = b4.w;
    __syncthreads();
#pragma unroll
    for (int kk = 0; kk < 16; ++kk) {
      float4 av = *(const float4*)&As[kk][tm << 2];
      float4 bv = *(const float4*)&Bs[kk][tn << 2];
      float a_[4] = {av.x, av.y, av.z, av.w};
      float b_[4] = {bv.x, bv.y, bv.z, bv.w};
#pragma unroll
      for (int i = 0; i < 4; ++i)
#pragma unroll
        for (int j = 0; j < 4; ++j) acc[i][j] = fmaf(a_[i], b_[j], acc[i][j]);
    }
  }
#pragma unroll
  for (int i = 0; i < 4; ++i) {
    int row = bm + (tm << 2) + i;
    if (row >= M) continue;
#pragma unroll
    for (int j = 0; j < 4; ++j) {
      int col = bn + (tn << 2) + j;
      if (col >= N) continue;
      float r = acc[i][j];
      if (add) r += add[(size_t)row * N + col];
      if (act == 1) r = 1.0f / (1.0f + expf(-r));
      else if (act == 2) r = r / (1.0f + expf(-r));
      C[(size_t)row * N + col] = r;
    }
  }
}

// ---------------- activations: v=silu, a1=silu, beta=sigmoid ----------------
__global__ void act_split(const float* __restrict__ C1, float* __restrict__ vb,
                          float* __restrict__ a1s, float* __restrict__ betab) {
  int idx = blockIdx.x * 256 + threadIdx.x;
  if (idx >= T_SEQ * 193) return;
  int t = idx / 193, j = idx % 193;
  if (j < 64) {
    float x = C1[(size_t)t * C1LD + 128 + j];
    vb[(size_t)t * DV + j] = siluf_(x);
  } else if (j < 192) {
    float x = C1[(size_t)t * C1LD + 192 + (j - 64)];
    a1s[(size_t)t * DKP + (j - 64)] = siluf_(x);
  } else {
    betab[t] = sigmoidf_(C1[(size_t)t * C1LD + 320]);
  }
}

// ---------------- PoPE: f32 phase arithmetic (matches numpy), accurate trig ----------------
__global__ __launch_bounds__(256) void pope_kernel(const float* __restrict__ C1,
                                                   const float* __restrict__ freq,
                                                   const float* __restrict__ shift,
                                                   float* __restrict__ qb, float* __restrict__ kb) {
  int idx = blockIdx.x * 256 + threadIdx.x;
  if (idx >= T_SEQ * DK) return;
  int t = idx >> 6;
  int i = idx & 63;
  const double TWO_PI = 6.283185307179586476925286766559;
  const double INV_TWO_PI = 0.15915494309189533576888376337251;
  float phiq = (float)t * freq[i];          // f32 multiply (matches numpy)
  float phik = phiq + shift[i];             // f32 add (matches numpy)
  float xq = C1[(size_t)t * C1LD + i];
  float muq = xq > 15.f ? xq : log1pf(expf(xq));
  double w = (double)phiq * INV_TWO_PI;
  w -= floor(w);
  float aq = (float)(w * TWO_PI);
  qb[(size_t)t * DKP + i] = muq * cosf(aq);
  qb[(size_t)t * DKP + 64 + i] = muq * sinf(aq);
  float xk = C1[(size_t)t * C1LD + DK + i];
  float muk = xk > 15.f ? xk : log1pf(expf(xk));
  double wk = (double)phik * INV_TWO_PI;
  wk -= floor(wk);
  float ak = (float)(wk * TWO_PI);
  kb[(size_t)t * DKP + i] = muk * cosf(ak);
  kb[(size_t)t * DKP + 64 + i] = muk * sinf(ak);
}

// ================= chunked scan (DPP rotate-reduce, no LDS-pipe traffic) =================
// Layout: 16 lanes per column, 8 k-dims per lane. fstate/sinbuf layout: [chunk][col][row]
// (coalesced for all producers/consumers).

// One recurrence step on already-loaded values (loads stay flat in the caller's loop).
__device__ __forceinline__ void pa_step(float s[8], float4 k0, float4 k1, float4 a0,
                                        float4 a1, float vt, float bt) {
  s[0] *= a0.x; s[1] *= a0.y; s[2] *= a0.z; s[3] *= a0.w;
  s[4] *= a1.x; s[5] *= a1.y; s[6] *= a1.z; s[7] *= a1.w;
  float e0 = fmaf(s[1], k0.y, s[0] * k0.x);
  float e1 = fmaf(s[3], k0.w, s[2] * k0.z);
  float e2 = fmaf(s[5], k1.y, s[4] * k1.x);
  float e3 = fmaf(s[7], k1.w, s[6] * k1.z);
  float d = sum16((e0 + e1) + (e2 + e3));
  float cf = bt * (vt - d);
  s[0] = fmaf(cf, k0.x, s[0]); s[1] = fmaf(cf, k0.y, s[1]);
  s[2] = fmaf(cf, k0.z, s[2]); s[3] = fmaf(cf, k0.w, s[3]);
  s[4] = fmaf(cf, k1.x, s[4]); s[5] = fmaf(cf, k1.y, s[5]);
  s[6] = fmaf(cf, k1.z, s[6]); s[7] = fmaf(cf, k1.w, s[7]);
}

// Pass A: tasks 0..127 basis columns (waves 0..31), 128..191 driven columns (waves 32..47).
// 2-deep software pipeline: register sets A (step t) / B (step t+1); loads for t+2 issued
// before step-A compute, loads for t+3 before step-B (flat named float4s, r7-proven style).
__global__ __launch_bounds__(64) void scan_passA(const float* __restrict__ kb,
                                                 const float* __restrict__ alphab,
                                                 const float* __restrict__ vb,
                                                 const float* __restrict__ betab,
                                                 float* __restrict__ PT,
                                                 float* __restrict__ fstate) {
  const int chunk = blockIdx.x;
  const int w = blockIdx.y;            // 0..47
  const int l = threadIdx.x;
  const int sl = l & 15;
  const int task = w * 4 + (l >> 4);   // 0..191; isP is wave-uniform (128 % 4 == 0)
  const bool isP = (task < 128);
  const int c = isP ? 0 : (task - 128);
  const float* kc = kb + (size_t)chunk * CHUNK * DKP + sl * 8;
  const float* ac = alphab + (size_t)chunk * CHUNK * DKP + sl * 8;
  const float* vcol = vb + (size_t)chunk * CHUNK * DV + c;
  const float* bp = betab + (size_t)chunk * CHUNK;
  float s[8];
#pragma unroll
  for (int i = 0; i < 8; ++i) s[i] = (isP && (sl * 8 + i == task)) ? 1.f : 0.f;
  // set A = step 0, set B = step 1
  float4 kA0 = *(const float4*)kc, kA1 = *(const float4*)(kc + 4);
  float4 aA0 = *(const float4*)ac, aA1 = *(const float4*)(ac + 4);
  float vA = isP ? 0.f : vcol[0];
  float bA = bp[0];
  float4 kB0 = *(const float4*)(kc + DKP), kB1 = *(const float4*)(kc + DKP + 4);
  float4 aB0 = *(const float4*)(ac + DKP), aB1 = *(const float4*)(ac + DKP + 4);
  float vB = isP ? 0.f : vcol[DV];
  float bB = bp[1];
  for (int t = 0; t < CHUNK; t += 2) {
    const int t2 = (t + 2 < CHUNK) ? t + 2 : CHUNK - 1;
    float4 nk0 = *(const float4*)(kc + (size_t)t2 * DKP);
    float4 nk1 = *(const float4*)(kc + (size_t)t2 * DKP + 4);
    float4 na0 = *(const float4*)(ac + (size_t)t2 * DKP);
    float4 na1 = *(const float4*)(ac + (size_t)t2 * DKP + 4);
    float nv = isP ? 0.f : vcol[(size_t)t2 * DV];
    float nb = bp[t2];
    pa_step(s, kA0, kA1, aA0, aA1, vA, bA);
    kA0 = nk0; kA1 = nk1; aA0 = na0; aA1 = na1; vA = nv; bA = nb;
    const int t3 = (t + 3 < CHUNK) ? t + 3 : CHUNK - 1;
    float4 mk0 = *(const float4*)(kc + (size_t)t3 * DKP);
    float4 mk1 = *(const float4*)(kc + (size_t)t3 * DKP + 4);
    float4 ma0 = *(const float4*)(ac + (size_t)t3 * DKP);
    float4 ma1 = *(const float4*)(ac + (size_t)t3 * DKP + 4);
    float mv = isP ? 0.f : vcol[(size_t)t3 * DV];
    float mb = bp[t3];
    pa_step(s, kB0, kB1, aB0, aB1, vB, bB);
    kB0 = mk0; kB1 = mk1; aB0 = ma0; aB1 = ma1; vB = mv; bB = mb;
  }
  if (isP) {
    float* dst = PT + (size_t)chunk * 16384 + (size_t)task * 128 + sl * 8;
    *(float4*)dst = make_float4(s[0], s[1], s[2], s[3]);
    *(float4*)(dst + 4) = make_float4(s[4], s[5], s[6], s[7]);
  } else {
    float* fd = fstate + (size_t)chunk * 8192 + (size_t)c * 128 + sl * 8;
    *(float4*)fd = make_float4(s[0], s[1], s[2], s[3]);
    *(float4*)(fd + 4) = make_float4(s[4], s[5], s[6], s[7]);
  }
}

// Combine v3: per column c, sequentially s_in(j+1) = P_j s_in(j) + f_j.
// 1024 threads = 128 rows x 8 K-eighths; 16-float register prefetch per thread (no spill);
// LDS tree-reduce of the 8 partials. fstate/sinbuf in [chunk][col][row] (coalesced).
__global__ __launch_bounds__(1024) void scan_combine(const float* __restrict__ PT,
                                                     const float* __restrict__ fstate,
                                                     float* __restrict__ sinbuf) {
  const int c = blockIdx.x;            // 0..63
  const int tid = threadIdx.x;
  const int r = tid & 127;             // row
  const int q = tid >> 7;              // K-eighth 0..7
  __shared__ float sv[128];
  __shared__ float part[8][128];
  const float* Pb = PT + (size_t)q * 2048 + r;  // + j*16384 + i*128
  float bufA[16], bufB[16];
#pragma unroll
  for (int i = 0; i < 16; ++i) bufA[i] = Pb[(size_t)i * 128];
  float s = 0.f;
#define CITER(J, CUR, NXT)                                                         \
  {                                                                                \
    float fJ = 0.f;                                                                \
    if (q == 0) {                                                                  \
      sinbuf[(size_t)(J) * 8192 + (size_t)c * 128 + r] = s;                        \
      sv[r] = s;                                                                   \
      fJ = fstate[(size_t)(J) * 8192 + (size_t)c * 128 + r];                       \
    }                                                                              \
    __syncthreads();                                                               \
    int jn = ((J) + 1 < NCHUNK) ? (J) + 1 : NCHUNK - 1;                            \
    const float* Pn = Pb + (size_t)jn * 16384;                                     \
    _Pragma("unroll")                                                              \
    for (int i = 0; i < 16; ++i) NXT[i] = Pn[(size_t)i * 128];                     \
    float a0 = 0.f, a1 = 0.f, a2 = 0.f, a3 = 0.f;                                  \
    _Pragma("unroll")                                                              \
    for (int i = 0; i < 16; i += 4) {                                              \
      a0 = fmaf(CUR[i], sv[q * 16 + i], a0);                                       \
      a1 = fmaf(CUR[i + 1], sv[q * 16 + i + 1], a1);                               \
      a2 = fmaf(CUR[i + 2], sv[q * 16 + i + 2], a2);                               \
      a3 = fmaf(CUR[i + 3], sv[q * 16 + i + 3], a3);                               \
    }                                                                              \
    part[q][r] = (a0 + a1) + (a2 + a3);                                            \
    __syncthreads();                                                               \
    if (q == 0) {                                                                  \
      float t8 = ((part[0][r] + part[1][r]) + (part[2][r] + part[3][r])) +         \
                 ((part[4][r] + part[5][r]) + (part[6][r] + part[7][r]));          \
      s = t8 + fJ;                                                                 \
    }                                                                              \
  }
  for (int j = 0; j < NCHUNK; j += 2) {
    CITER(j, bufA, bufB)
    CITER(j + 1, bufB, bufA)
  }
#undef CITER
}

// Pass B: 4 columns/wave, r7-proven structure: next-iteration values loaded as named
// float4s at loop top (1-deep prefetch the compiler keeps in registers), compute after.
__global__ __launch_bounds__(64) void scan_passB(const float* __restrict__ qb,
                                                 const float* __restrict__ kb,
                                                 const float* __restrict__ alphab,
                                                 const float* __restrict__ vb,
                                                 const float* __restrict__ betab,
                                                 const float* __restrict__ sinbuf,
                                                 float* __restrict__ ob) {
  const int chunk = blockIdx.x;
  const int l = threadIdx.x;
  const int sl = l & 15;
  const int c = blockIdx.y * 4 + (l >> 4);  // 0..63
  const float* kc = kb + (size_t)chunk * CHUNK * DKP + sl * 8;
  const float* ac = alphab + (size_t)chunk * CHUNK * DKP + sl * 8;
  const float* qc = qb + (size_t)chunk * CHUNK * DKP + sl * 8;
  const float* vcol = vb + (size_t)chunk * CHUNK * DV + c;
  const float* bp = betab + (size_t)chunk * CHUNK;
  float* ocol = ob + (size_t)chunk * CHUNK * DV + c;
  float s[8];
  const float* sbase = sinbuf + (size_t)chunk * 8192 + (size_t)c * 128 + sl * 8;
  float4 si0 = *(const float4*)sbase, si1 = *(const float4*)(sbase + 4);
  s[0] = si0.x; s[1] = si0.y; s[2] = si0.z; s[3] = si0.w;
  s[4] = si1.x; s[5] = si1.y; s[6] = si1.z; s[7] = si1.w;
  float4 k0 = *(const float4*)kc, k1 = *(const float4*)(kc + 4);
  float4 a0 = *(const float4*)ac, a1 = *(const float4*)(ac + 4);
  float4 q0 = *(const float4*)qc, q1 = *(const float4*)(qc + 4);
  float vt = vcol[0], bt = bp[0];
  for (int t = 0; t < CHUNK; ++t) {
    const int tn = (t + 1 < CHUNK) ? t + 1 : CHUNK - 1;
    float4 nk0 = *(const float4*)(kc + (size_t)tn * DKP);
    float4 nk1 = *(const float4*)(kc + (size_t)tn * DKP + 4);
    float4 na0 = *(const float4*)(ac + (size_t)tn * DKP);
    float4 na1 = *(const float4*)(ac + (size_t)tn * DKP + 4);
    float4 nq0 = *(const float4*)(qc + (size_t)tn * DKP);
    float4 nq1 = *(const float4*)(qc + (size_t)tn * DKP + 4);
    float nv = vcol[(size_t)tn * DV];
    float nb = bp[tn];
    s[0] *= a0.x; s[1] *= a0.y; s[2] *= a0.z; s[3] *= a0.w;
    s[4] *= a1.x; s[5] *= a1.y; s[6] *= a1.z; s[7] *= a1.w;
    float e0 = fmaf(s[1], k0.y, s[0] * k0.x);
    float e1 = fmaf(s[3], k0.w, s[2] * k0.z);
    float e2 = fmaf(s[5], k1.y, s[4] * k1.x);
    float e3 = fmaf(s[7], k1.w, s[6] * k1.z);
    float d = sum16((e0 + e1) + (e2 + e3));
    float cf = bt * (vt - d);
    s[0] = fmaf(cf, k0.x, s[0]); s[1] = fmaf(cf, k0.y, s[1]);
    s[2] = fmaf(cf, k0.z, s[2]); s[3] = fmaf(cf, k0.w, s[3]);
    s[4] = fmaf(cf, k1.x, s[4]); s[5] = fmaf(cf, k1.y, s[5]);
    s[6] = fmaf(cf, k1.z, s[6]); s[7] = fmaf(cf, k1.w, s[7]);
    float f0 = fmaf(s[1], q0.y, s[0] * q0.x);
    float f1 = fmaf(s[3], q0.w, s[2] * q0.z);
    float f2 = fmaf(s[5], q1.y, s[4] * q1.x);
    float f3 = fmaf(s[7], q1.w, s[6] * q1.z);
    float e = sum16((f0 + f1) + (f2 + f3));
    if (sl == 0) ocol[(size_t)t * DV] = e;
    k0 = nk0; k1 = nk1; a0 = na0; a1 = na1; q0 = nq0; q1 = nq1; vt = nv; bt = nb;
  }
}

// ---------------- post: og16 = bf16(rmsnorm(o)*pnw*sigmoid(gate_pre)) ----------------
__global__ __launch_bounds__(256) void post_kernel(const float* __restrict__ ob,
                                                   const float* __restrict__ C1,
                                                   const float* __restrict__ pnw,
                                                   unsigned short* __restrict__ og16) {
  int row = blockIdx.x * 4 + (threadIdx.x >> 6);
  int c = threadIdx.x & 63;
  float o = ob[(size_t)row * DV + c];
  float ss = wave_sum(o * o);
  float scale = 1.0f / sqrtf(ss * (1.0f / DV) + RMS_EPS);
  float g = sigmoidf_(C1[(size_t)row * C1LD + 321 + c]);
  og16[(size_t)row * DV + c] = f2bf(o * scale * pnw[c] * g);
}

// ---------------- rmsnorm over d=1024 rows -> bf16 ----------------
__global__ __launch_bounds__(256) void rmsnorm_rows(const float* __restrict__ x,
                                                    const float* __restrict__ w,
                                                    unsigned short* __restrict__ y) {
  int row = blockIdx.x;
  const float4* x4 = (const float4*)(x + (size_t)row * D_MODEL);
  const float4* w4 = (const float4*)w;
  float4 v = x4[threadIdx.x];
  float ss = v.x * v.x + v.y * v.y + v.z * v.z + v.w * v.w;
  ss = wave_sum(ss);
  __shared__ float red[4];
  if ((threadIdx.x & 63) == 0) red[threadIdx.x >> 6] = ss;
  __syncthreads();
  float tot = red[0] + red[1] + red[2] + red[3];
  float scale = 1.0f / sqrtf(tot * (1.0f / D_MODEL) + RMS_EPS);
  float4 wv = w4[threadIdx.x];
  uint2 o;
  o.x = (unsigned)f2bf(v.x * scale * wv.x) | ((unsigned)f2bf(v.y * scale * wv.y) << 16);
  o.y = (unsigned)f2bf(v.z * scale * wv.z) | ((unsigned)f2bf(v.w * scale * wv.w) << 16);
  ((uint2*)(y + (size_t)row * D_MODEL))[threadIdx.x] = o;
}

// ---------------- GU16 = bf16(G * U) ----------------
__global__ void mul_to_bf16(const float* __restrict__ G, const float* __restrict__ U,
                            unsigned short* __restrict__ O, int n4) {
  int i = blockIdx.x * 256 + threadIdx.x;
  if (i >= n4) return;
  float4 g = ((const float4*)G)[i];
  float4 u = ((const float4*)U)[i];
  uint2 o;
  o.x = (unsigned)f2bf(g.x * u.x) | ((unsigned)f2bf(g.y * u.y) << 16);
  o.y = (unsigned)f2bf(g.z * u.z) | ((unsigned)f2bf(g.w * u.w) << 16);
  ((uint2*)O)[i] = o;
}

extern "C" void kernel_launch(void* const* d_in, const int* in_sizes, int n_in,
                              void* d_out, int out_size, void* d_ws, size_t ws_size,
                              hipStream_t stream) {
  const float* x_seq = (const float*)d_in[0];
  const float* W_q = (const float*)d_in[1];
  const float* W_k = (const float*)d_in[2];
  const float* W_v = (const float*)d_in[3];
  const float* pope_delta = (const float*)d_in[4];
  const float* W_a1 = (const float*)d_in[5];
  const float* W_a2 = (const float*)d_in[6];
  const float* W_beta = (const float*)d_in[7];
  const float* pnw = (const float*)d_in[8];
  const float* out_gate_W = (const float*)d_in[9];
  const float* W_out = (const float*)d_in[10];
  const float* ffn_norm_w = (const float*)d_in[11];
  const float* Wg = (const float*)d_in[12];
  const float* Wu = (const float*)d_in[13];
  const float* Wd = (const float*)d_in[14];
  float* out = (float*)d_out;

  float* F = (float*)d_ws;
  float* freq_f = F;                      // 64
  float* shift_f = F + 64;                // 64
  size_t o = 256;
  unsigned short* Wcat16 = (unsigned short*)(F + o); o += 262144;   // 512x1024 bf16
  unsigned short* Wg16   = (unsigned short*)(F + o); o += 524288;   // 1024x1024 bf16
  unsigned short* Wu16   = (unsigned short*)(F + o); o += 524288;
  unsigned short* Wd16   = (unsigned short*)(F + o); o += 524288;
  unsigned short* Wout16 = (unsigned short*)(F + o); o += 32768;    // 1024x64 bf16
  unsigned short* og16   = (unsigned short*)(F + o); o += 262144;   // 8192x64 bf16
  float* BIG = F + o;
  // phase 1 layout (within BIG)
  float* C1 = BIG;                        // 8192x512 f32
  float* qb = C1 + 4194304;               // 8192x128
  float* kb = qb + 1048576;
  float* alphab = kb + 1048576;
  float* a1s = alphab + 1048576;
  float* vb = a1s + 1048576;              // 8192x64
  float* betab = vb + 524288;             // 8192
  float* ob = betab + 8192;               // 8192x64
  float* PT = ob + 524288;                // 64x128x128
  float* fstate = PT + 1048576;           // 64x64x128 [chunk][col][row]
  float* sinbuf = fstate + 524288;        // 64x64x128 [chunk][col][row]
  unsigned short* x16 = (unsigned short*)(sinbuf + 524288);  // 8192x1024 bf16
  // phase 2 layout (reuses BIG; phase-1 buffers dead by then)
  unsigned short* hb16 = (unsigned short*)BIG;   // 8192x1024 bf16
  unsigned short* GU16 = (unsigned short*)BIG;   // aliases hb16 (dead after Wu GEMM)
  float* Gb = BIG + 4194304;              // 8192x1024 f32
  float* Ub = Gb + 8388608;               // 8192x1024 f32

  (void)in_sizes; (void)n_in; (void)out_size; (void)ws_size;

  init_tables<<<1, 64, 0, stream>>>(pope_delta, freq_f, shift_f);
  build_wcat16<<<(512 * 1024 + 255) / 256, 256, 0, stream>>>(W_q, W_k, W_v, W_a1, W_beta,
                                                             out_gate_W, Wcat16);
  conv_bf16<<<(2097152 + 255) / 256, 256, 0, stream>>>(x_seq, x16, 2097152);
  conv_weights<<<(802816 + 255) / 256, 256, 0, stream>>>(Wg, Wu, Wd, W_out,
                                                         Wg16, Wu16, Wd16, Wout16);
  // fused projection: C1 = x16 @ Wcat16^T  (8192 x 512, K=1024)
  gemm_bf16<<<dim3(64, 4), 256, 0, stream>>>(x16, Wcat16, nullptr, C1, T_SEQ, 512, 1024, 0);
  act_split<<<(T_SEQ * 193 + 255) / 256, 256, 0, stream>>>(C1, vb, a1s, betab);
  gemm_f32<<<dim3(128, 2), 256, 0, stream>>>(a1s, W_a2, nullptr, alphab, T_SEQ, DKP, DKP, 1);
  pope_kernel<<<(T_SEQ * DK + 255) / 256, 256, 0, stream>>>(C1, freq_f, shift_f, qb, kb);
  // chunked scan
  scan_passA<<<dim3(NCHUNK, 48), 64, 0, stream>>>(kb, alphab, vb, betab, PT, fstate);
  scan_combine<<<64, 1024, 0, stream>>>(PT, fstate, sinbuf);
  scan_passB<<<dim3(NCHUNK, 16), 64, 0, stream>>>(qb, kb, alphab, vb, betab, sinbuf, ob);
  post_kernel<<<T_SEQ / 4, 256, 0, stream>>>(ob, C1, pnw, og16);
  // xres = x_seq + og @ W_out^T  (8192 x 1024, K=64) -> d_out
  gemm_bf16<<<dim3(64, 8), 256, 0, stream>>>(og16, Wout16, x_seq, out, T_SEQ, D_MODEL, 64, 0);
  rmsnorm_rows<<<T_SEQ, 256, 0, stream>>>(out, ffn_norm_w, hb16);
  // FFN
  gemm_bf16<<<dim3(64, 8), 256, 0, stream>>>(hb16, Wg16, nullptr, Gb, T_SEQ, D_MODEL, D_MODEL, 2);
  gemm_bf16<<<dim3(64, 8), 256, 0, stream>>>(hb16, Wu16, nullptr, Ub, T_SEQ, D_MODEL, D_MODEL, 0);
  mul_to_bf16<<<(2097152 + 255) / 256, 256, 0, stream>>>(Gb, Ub, GU16, 2097152);
  gemm_bf16<<<dim3(64, 8), 256, 0, stream>>>(GU16, Wd16, out, out, T_SEQ, D_MODEL, D_MODEL, 0);
}